// Round 4
// baseline (338.469 us; speedup 1.0000x reference)
//
#include <hip/hip_runtime.h>

// Problem dims
#define S_ 32
#define T_ 64
#define B_ 64
#define V_ 32000
#define E_ 128
#define H_ 128
#define G_ 128
#define C_ 5

typedef short s8v __attribute__((ext_vector_type(8)));   // 8 bf16 payload
typedef __bf16 b8v __attribute__((ext_vector_type(8)));
typedef float f32x4 __attribute__((ext_vector_type(4)));

// --- MFMA wrapper: tolerate either builtin operand signature (short8 or bf16x8)
template <typename V>
__device__ inline auto mfma_sel(V a, V b, f32x4 c, int)
    -> decltype(__builtin_amdgcn_mfma_f32_16x16x32_bf16(a, b, c, 0, 0, 0)) {
  return __builtin_amdgcn_mfma_f32_16x16x32_bf16(a, b, c, 0, 0, 0);
}
template <typename V>
__device__ inline f32x4 mfma_sel(V a, V b, f32x4 c, long) {
  return __builtin_amdgcn_mfma_f32_16x16x32_bf16(
      __builtin_bit_cast(b8v, a), __builtin_bit_cast(b8v, b), c, 0, 0, 0);
}
__device__ inline f32x4 mfma16(s8v a, s8v b, f32x4 c) { return mfma_sel(a, b, c, 0); }

__device__ inline float b2f(unsigned short u) {
  union { unsigned int i; float f; } v; v.i = ((unsigned int)u) << 16; return v.f;
}
// round-to-nearest (ties away) — 2 instr; RNE tie diff is <=1ulp, irrelevant at 2% tol
__device__ inline unsigned short f2b(float f) {
  union { float f; unsigned int i; } v; v.f = f;
  return (unsigned short)((v.i + 0x8000u) >> 16);
}
// full-RNE for the precomputed tables (cheap there, done once per element)
__device__ inline unsigned short f2b_rne(float f) {
  union { float f; unsigned int i; } v; v.f = f;
  unsigned int r = (v.i + 0x7fffu + ((v.i >> 16) & 1u)) >> 16;
  return (unsigned short)r;
}
__device__ inline s8v cvt8(const float* p) {
  const float4 a = *(const float4*)p;
  const float4 b = *(const float4*)(p + 4);
  s8v r;
  r[0] = (short)f2b_rne(a.x); r[1] = (short)f2b_rne(a.y);
  r[2] = (short)f2b_rne(a.z); r[3] = (short)f2b_rne(a.w);
  r[4] = (short)f2b_rne(b.x); r[5] = (short)f2b_rne(b.y);
  r[6] = (short)f2b_rne(b.z); r[7] = (short)f2b_rne(b.w);
  return r;
}
// division-free activations: raw v_rcp_f32 + v_exp_f32 (1 instr each).
__device__ inline float fsigm(float x) {
  return __builtin_amdgcn_rcpf(1.f + __builtin_amdgcn_exp2f(-1.44269504f * x));
}
__device__ inline float ftanh(float x) {
  return 1.f - 2.f * __builtin_amdgcn_rcpf(1.f + __builtin_amdgcn_exp2f(2.88539008f * x));
}

// LDS-only barrier: waits LDS ops, does NOT drain vmcnt — global loads issued
// before this stay in flight across it (cross-wave data here is LDS-only).
__device__ inline void lds_barrier() {
  asm volatile("s_waitcnt lgkmcnt(0)\n\ts_barrier" ::: "memory");
}

// ============================================================================
// K1: gtab[v][c] = sum_e emb[v][e]*Wih_intra[c][e] + bih[c] (+bhh[c] folded for
// r,z gates). MFMA GEMM: 500 blocks own a 64-row emb tile and iterate ALL 6
// N-chunks. Blocks 500..503: transpose W_W_intra. Blocks 504..507: convert
// Wih_inter fp32 -> bf16 (for the fused xgi MFMA in k_attn).
// ============================================================================
__global__ __launch_bounds__(256) void k_gtab(
    const float* __restrict__ emb,
    const float* __restrict__ wih,   // [768][128] fp32
    const float* __restrict__ bih,   // [768] fp32
    const float* __restrict__ bhh,   // [768] fp32 (r,z folded; n NOT)
    const float* __restrict__ wwi,   // [256][256] fp32 (h-major)
    const float* __restrict__ wihI,  // [768][256] fp32 (inter input weights)
    unsigned short* __restrict__ gtab,   // [V][768] bf16
    unsigned short* __restrict__ wta,    // [256][256] bf16 (n-major)
    unsigned short* __restrict__ wib)    // [768][256] bf16
{
  __shared__ __align__(16) unsigned short smem[64 * 264];  // union: alds / tbuf
  const int bid = blockIdx.x, tid = threadIdx.x;
  if (bid >= 504) {  // wihI fp32 -> bf16, 4 blocks
    const int cb = bid - 504;
    for (int i = 0; i < 48; ++i) {
      int e4 = cb * 12288 + i * 256 + tid;  // float4 index
      float4 v = *(const float4*)&wihI[(size_t)e4 * 4];
      ushort4 u;
      u.x = f2b_rne(v.x); u.y = f2b_rne(v.y); u.z = f2b_rne(v.z); u.w = f2b_rne(v.w);
      *(ushort4*)&wib[(size_t)e4 * 4] = u;
    }
    return;
  }
  if (bid >= 500) {  // LDS-tiled transpose, 4 blocks x 64 n-rows
    const int n0 = (bid - 500) * 64;
    for (int i = 0; i < 64; ++i) {
      int cid = i * 256 + tid;
      int k = cid >> 6, nl = cid & 63;
      smem[nl * 264 + k] = f2b_rne(wwi[k * 256 + n0 + nl]);  // coalesced read
    }
    __syncthreads();
    for (int i = 0; i < 8; ++i) {
      int cid = i * 256 + tid;
      int nl = cid >> 5, k8 = cid & 31;
      *(int4*)&wta[(size_t)(n0 + nl) * 256 + k8 * 8] =
          *(const int4*)&smem[nl * 264 + k8 * 8];            // coalesced write
    }
    return;
  }
  const int vbase = bid * 64;
  for (int i = 0; i < 8; ++i) {
    int cid = i * 256 + tid;           // 2048 chunks of 4 floats
    int row = cid >> 5, kc = cid & 31;
    float4 v = *(const float4*)&emb[(size_t)(vbase + row) * 128 + kc * 4];
    ushort4 u;
    u.x = f2b_rne(v.x); u.y = f2b_rne(v.y); u.z = f2b_rne(v.z); u.w = f2b_rne(v.w);
    *(ushort4*)&smem[row * 136 + kc * 4] = u;
  }
  __syncthreads();
  const int w = tid >> 6, l = tid & 63, q = l >> 4, ln = l & 15;
  // hoist all A fragments (16 s8v = 64 VGPR) — reused across 6 N-chunks
  s8v af[4][4];
  for (int mt = 0; mt < 4; ++mt)
    for (int kf = 0; kf < 4; ++kf)
      af[mt][kf] = *(const s8v*)&smem[(mt * 16 + ln) * 136 + kf * 32 + q * 8];
  for (int nchunk = 0; nchunk < 6; ++nchunk) {
    const int nbase = nchunk * 128;
    s8v bf[2][4];
    float bias[2];
    for (int nt = 0; nt < 2; ++nt) {
      int c = nbase + (w * 2 + nt) * 16 + ln;
      int g = (c < 384) ? c : (c - 384);       // gate index within direction
      bias[nt] = bih[c] + (g < 256 ? bhh[c] : 0.f);  // fold r,z recurrent bias
      for (int kf = 0; kf < 4; ++kf)
        bf[nt][kf] = cvt8(&wih[(size_t)c * 128 + kf * 32 + q * 8]);
    }
    for (int mt = 0; mt < 4; ++mt) {
      for (int nt = 0; nt < 2; ++nt) {
        f32x4 acc = {0.f, 0.f, 0.f, 0.f};
        for (int kf = 0; kf < 4; ++kf) acc = mfma16(af[mt][kf], bf[nt][kf], acc);
        const int col = nbase + (w * 2 + nt) * 16 + ln;
        for (int r = 0; r < 4; ++r) {
          const int row = vbase + mt * 16 + q * 4 + r;
          gtab[(size_t)row * 768 + col] = f2b_rne(acc[r] + bias[nt]);
        }
      }
    }
  }
}

// ============================================================================
// K2: intra biGRU. Grid 512 = (s, dir, b-OCTET of 8): N=8 real batches per
// block (lanes ln and ln+8 duplicate a batch — identical values, benign).
// 2 blocks/CU co-residency: two independent recurrent chains per CU so one
// chain's barrier/LDS/MFMA stalls are filled by the other's issue.
// Depth-3 token-gather pipeline (4 static register slots, x4 unroll).
// ============================================================================
__global__ __launch_bounds__(512) void k_intra(
    const int* __restrict__ tokens,
    const unsigned short* __restrict__ gtab,  // bf16, r/z biases folded
    const float* __restrict__ whh,            // [2][384][128] fp32
    const float* __restrict__ bhh,            // [2][384] fp32 (n-gate used)
    unsigned short* __restrict__ iout)        // [S*T*B][256] bf16 internal
{
  const int bid = blockIdx.x;
  const int s = bid >> 4, dir = (bid >> 3) & 1, bo = bid & 7;
  const int bbase = bo * 8;
  const int tid = threadIdx.x;
  const int w = tid >> 6, l = tid & 63, q = l >> 4, ln = l & 15;
  const int gbase = w * 16, g0 = gbase + q * 4;

  __shared__ __align__(16) unsigned short hb[2][16 * 136];
  __shared__ int tokl[T_ * 16];

  for (int i = tid; i < 2 * 16 * 136; i += 512) ((unsigned short*)hb)[i] = 0;
  for (int i = tid; i < T_ * 16; i += 512) {
    int t = i >> 4, bl = i & 15;               // bl and bl+8 duplicate a batch
    tokl[i] = tokens[(s * T_ + t) * B_ + bbase + (bl & 7)] * 768 + dir * 384;
  }

  s8v af[3][4];
  float hbn[4];
  const float* whd = whh + (size_t)dir * (384 * 128);
  const float* bhd = bhh + dir * 384;
  for (int g3 = 0; g3 < 3; ++g3) {
    const int R = g3 * 128 + gbase;
    for (int kf = 0; kf < 4; ++kf)
      af[g3][kf] = cvt8(&whd[(size_t)(R + ln) * 128 + kf * 32 + q * 8]);
  }
  for (int r = 0; r < 4; ++r) hbn[r] = bhd[256 + gbase + q * 4 + r];  // n-gate only
  float h[4] = {0.f, 0.f, 0.f, 0.f};
  const int b = bbase + (ln & 7);
  __syncthreads();

  // --- depth-3 gather pipeline, 4 static register slots ---
  ushort4 Xr[4], Xz[4], Xn[4];
#define GLOAD_I(slot, st)                                                   \
  do {                                                                      \
    int tt_ = (st) > (T_ - 1) ? (T_ - 1) : (st);                            \
    int tg_ = dir ? (T_ - 1 - tt_) : tt_;                                   \
    const unsigned short* gp_ =                                             \
        gtab + (size_t)(tokl[tg_ * 16 + ln] + g0);                          \
    Xr[slot] = *(const ushort4*)&gp_[0];                                    \
    Xz[slot] = *(const ushort4*)&gp_[128];                                  \
    Xn[slot] = *(const ushort4*)&gp_[256];                                  \
  } while (0)

  GLOAD_I(0, 0);
  GLOAD_I(1, 1);
  GLOAD_I(2, 2);

  int p = 0;
  for (int it = 0; it < T_ / 4; ++it) {
#pragma unroll
    for (int j = 0; j < 4; ++j) {
      const int step = it * 4 + j;
      const int t = dir ? (T_ - 1 - step) : step;
      GLOAD_I((j + 3) & 3, step + 3);   // prefetch 3 steps ahead

      s8v bfr[4];
      for (int kf = 0; kf < 4; ++kf)
        bfr[kf] = *(const s8v*)&hb[p][ln * 136 + kf * 32 + q * 8];
      f32x4 c0 = {0.f, 0.f, 0.f, 0.f}, c1 = c0, c2 = c0;
      for (int kf = 0; kf < 4; ++kf) {
        c0 = mfma16(af[0][kf], bfr[kf], c0);
        c1 = mfma16(af[1][kf], bfr[kf], c1);
        c2 = mfma16(af[2][kf], bfr[kf], c2);
      }

      const unsigned short* xrp = (const unsigned short*)&Xr[j];
      const unsigned short* xzp = (const unsigned short*)&Xz[j];
      const unsigned short* xnp = (const unsigned short*)&Xn[j];
      unsigned short hnb[4];
      for (int r = 0; r < 4; ++r) {
        float rr = fsigm(b2f(xrp[r]) + c0[r]);                 // bhh_r folded
        float zz = fsigm(b2f(xzp[r]) + c1[r]);                 // bhh_z folded
        float nn = ftanh(b2f(xnp[r]) + rr * (c2[r] + hbn[r])); // bhh_n inside r*()
        float hv = zz * (h[r] - nn) + nn;
        h[r] = hv;
        hnb[r] = f2b(hv);
      }
      ushort4 hv4; hv4.x = hnb[0]; hv4.y = hnb[1]; hv4.z = hnb[2]; hv4.w = hnb[3];
      *(ushort4*)&hb[p ^ 1][ln * 136 + g0] = hv4;
      if (ln < 8)
        *(ushort4*)&iout[((size_t)(s * T_ + t) * B_ + b) * 256 + dir * 128 + g0] = hv4;
      lds_barrier();
      p ^= 1;
    }
  }
#undef GLOAD_I
}

// ============================================================================
// K3 (fused attn + xgi): one pass over iout. Grid 256 = (s, b-group of 8).
// Full W_W_intra (128 KB) in LDS; flash-style single iout read; cross-wave
// merge through the freed W region; THEN the inter input-gate GEMM
// (xgi = sv @ WihI^T + biases) fused on the block's 8 sv rows via bf16 MFMA.
// ============================================================================
__global__ __launch_bounds__(512, 1) void k_attn(
    const unsigned short* __restrict__ iout,  // bf16 internal
    const unsigned short* __restrict__ wta,   // bf16 [256][256] n-major
    const float* __restrict__ bint,           // [256] fp32
    const float* __restrict__ proj,           // [256] fp32
    const unsigned short* __restrict__ wib,   // bf16 [768][256] (WihI)
    const float* __restrict__ bihI,           // [768] fp32
    const float* __restrict__ bhhI,           // [768] fp32
    float* __restrict__ xgi)                  // [2][2048][384] fp32
{
  __shared__ __align__(16) unsigned short wlds[256 * 256];  // 128 KB, XOR-swizzled
  __shared__ float lgbuf[8][16];
  __shared__ float lbuf[8][8];
  const int tid = threadIdx.x, bid = blockIdx.x;
  const int s = bid >> 3, b0 = (bid & 7) * 8;
  // stage full W (both halves)
  for (int i = 0; i < 16; ++i) {
    int cid = i * 512 + tid;          // 8192 16B chunks
    int n = cid >> 5, kc = cid & 31;
    *(int4*)&wlds[n * 256 + ((kc ^ (n & 15)) << 3)] =
        *(const int4*)&wta[(size_t)n * 256 + kc * 8];
  }
  const int w = tid >> 6, l = tid & 63, q = l >> 4, ln = l & 15;
  float bbv[16], ppv[16];
  for (int nt = 0; nt < 16; ++nt) {     // per-lane bias/proj for its n-cols
    bbv[nt] = bint[nt * 16 + ln];
    ppv[nt] = proj[nt * 16 + ln];
  }
  __syncthreads();

  float O[8][8];                        // [kf][j] weighted-sum accumulator
  for (int kf = 0; kf < 8; ++kf)
    for (int j = 0; j < 8; ++j) O[kf][j] = 0.f;
  float l_acc = 0.f;

  for (int tile = 0; tile < 4; ++tile) {  // wave w owns t = 8w .. 8w+7
    const int t = (w * 4 + tile) * 2 + (ln >> 3);
    const size_t row = (size_t)((s * T_ + t) * B_ + b0 + (ln & 7));
    s8v af[8];
    for (int kf = 0; kf < 8; ++kf)
      af[kf] = *(const s8v*)&iout[row * 256 + kf * 32 + q * 8];
    float p0 = 0.f, p1 = 0.f, p2 = 0.f, p3 = 0.f;
    for (int nt = 0; nt < 16; ++nt) {
      f32x4 c = {0.f, 0.f, 0.f, 0.f};
      for (int kf = 0; kf < 8; ++kf) {
        s8v bf = *(const s8v*)&wlds[(nt * 16 + ln) * 256 + (((kf * 4 + q) ^ ln) << 3)];
        c = mfma16(af[kf], bf, c);
      }
      p0 += ppv[nt] * ftanh(c[0] + bbv[nt]);
      p1 += ppv[nt] * ftanh(c[1] + bbv[nt]);
      p2 += ppv[nt] * ftanh(c[2] + bbv[nt]);
      p3 += ppv[nt] * ftanh(c[3] + bbv[nt]);
    }
    for (int d = 1; d < 16; d <<= 1) {   // reduce over n-col lanes
      p0 += __shfl_xor(p0, d); p1 += __shfl_xor(p1, d);
      p2 += __shfl_xor(p2, d); p3 += __shfl_xor(p3, d);
    }
    // remap logits (held per D-row q*4+r) to A-row layout via same-wave LDS
    if (ln == 0) {
      lgbuf[w][q * 4 + 0] = p0; lgbuf[w][q * 4 + 1] = p1;
      lgbuf[w][q * 4 + 2] = p2; lgbuf[w][q * 4 + 3] = p3;
    }
    const float lg = lgbuf[w][ln];       // logit for THIS lane's (t,b) row
    const float e = __builtin_amdgcn_exp2f(1.44269504f * lg);
    l_acc += e;
    for (int kf = 0; kf < 8; ++kf)
      for (int j = 0; j < 8; ++j)
        O[kf][j] += e * b2f((unsigned short)af[kf][j]);
  }
  // merge t-pair lanes (ln, ln+8): same b, same dims
  l_acc += __shfl_xor(l_acc, 8);
  for (int kf = 0; kf < 8; ++kf)
    for (int j = 0; j < 8; ++j) O[kf][j] += __shfl_xor(O[kf][j], 8);
  __syncthreads();                       // everyone done reading wlds
  float* obuf = (float*)wlds;            // overlay [0..64K): [8 waves][8 b][256 d]
  unsigned short* svl = (unsigned short*)(((char*)wlds) + 65536);  // [16][264] bf16
  if (ln < 8) {
    const int base = w * 2048 + ln * 256 + q * 8;
    for (int kf = 0; kf < 8; ++kf) {
      float4 v0; v0.x = O[kf][0]; v0.y = O[kf][1]; v0.z = O[kf][2]; v0.w = O[kf][3];
      float4 v1; v1.x = O[kf][4]; v1.y = O[kf][5]; v1.z = O[kf][6]; v1.w = O[kf][7];
      *(float4*)&obuf[base + kf * 32]     = v0;
      *(float4*)&obuf[base + kf * 32 + 4] = v1;
    }
    if (q == 0) lbuf[w][ln] = l_acc;
  }
  // zero pad rows 8..15 of svl (A-operand padding for the M=8 GEMM)
  {
    ushort4 z4; z4.x = 0; z4.y = 0; z4.z = 0; z4.w = 0;
    int rr = 8 + (tid >> 6), cc = (tid & 63) * 4;  // 8 rows x 256 cols, pad ignored
    *(ushort4*)&svl[rr * 264 + cc] = z4;
  }
  __syncthreads();
  // deterministic 8-way reduce + softmax normalize -> sv (bf16, into svl)
  const int idx = tid * 4;               // 2048 outputs / 512 threads
  const int bb_ = idx >> 8;
  float4 acc; acc.x = 0.f; acc.y = 0.f; acc.z = 0.f; acc.w = 0.f;
  float lsum = 0.f;
  for (int w8 = 0; w8 < 8; ++w8) {
    const float4 v = *(const float4*)&obuf[w8 * 2048 + idx];
    acc.x += v.x; acc.y += v.y; acc.z += v.z; acc.w += v.w;
    lsum += lbuf[w8][bb_];
  }
  const float inv = __builtin_amdgcn_rcpf(lsum);
  ushort4 u;
  u.x = f2b_rne(acc.x * inv); u.y = f2b_rne(acc.y * inv);
  u.z = f2b_rne(acc.z * inv); u.w = f2b_rne(acc.w * inv);
  *(ushort4*)&svl[bb_ * 264 + (idx & 255)] = u;
  __syncthreads();
  // ---- fused xgi GEMM: out[m=0..7][c=0..767] = sv . WihI[c] + bias ----
  s8v afx[8];
  for (int kf = 0; kf < 8; ++kf)
    afx[kf] = *(const s8v*)&svl[ln * 264 + kf * 32 + q * 8];
  for (int nt = 0; nt < 6; ++nt) {
    const int c = w * 96 + nt * 16 + ln;  // col 0..767
    const int dirI = (c >= 384) ? 1 : 0;
    const int g = c - dirI * 384;
    const float biasx = bihI[c] + (g < 256 ? bhhI[c] : 0.f);  // fold r,z
    f32x4 cacc = {0.f, 0.f, 0.f, 0.f};
    for (int kf = 0; kf < 8; ++kf) {
      s8v bfx = *(const s8v*)&wib[(size_t)c * 256 + kf * 32 + q * 8];
      cacc = mfma16(afx[kf], bfx, cacc);
    }
    if (q < 2) {                          // rows 0..7 are real sv rows
      for (int r = 0; r < 4; ++r) {
        const int m = q * 4 + r;
        xgi[((size_t)dirI * 2048 + s * B_ + b0 + m) * 384 + g] = cacc[r] + biasx;
      }
    }
  }
}

// ============================================================================
// K5: inter biGRU. Grid 8 = (dir, b-quad of 16). Depth-3 pipelined gate loads.
// ============================================================================
__global__ __launch_bounds__(512) void k_inter(
    const float* __restrict__ xgi,   // r,z biases folded
    const float* __restrict__ whh,   // [2][384][128] fp32
    const float* __restrict__ bhh,   // [2][384] fp32 (n-gate used)
    float* __restrict__ io2)         // [S*B][256] fp32
{
  const int bid = blockIdx.x;
  const int dir = bid >> 2, bq = bid & 3, bbase = bq * 16;
  const int tid = threadIdx.x;
  const int w = tid >> 6, l = tid & 63, q = l >> 4, ln = l & 15;
  const int gbase = w * 16, g0 = gbase + q * 4;
  __shared__ __align__(16) unsigned short hb[2][16 * 136];
  for (int i = tid; i < 2 * 16 * 136; i += 512) ((unsigned short*)hb)[i] = 0;
  s8v af[3][4];
  float hbn[4];
  const float* whd = whh + (size_t)dir * (384 * 128);
  const float* bhd = bhh + dir * 384;
  for (int g3 = 0; g3 < 3; ++g3) {
    const int R = g3 * 128 + gbase;
    for (int kf = 0; kf < 4; ++kf)
      af[g3][kf] = cvt8(&whd[(size_t)(R + ln) * 128 + kf * 32 + q * 8]);
  }
  for (int r = 0; r < 4; ++r) hbn[r] = bhd[256 + gbase + q * 4 + r];
  float h[4] = {0.f, 0.f, 0.f, 0.f};
  const int b = bbase + ln;
  __syncthreads();

  float4 Vr[4], Vz[4], Vn[4];
#define GLOAD_S(slot, st)                                                   \
  do {                                                                      \
    int tt_ = (st) > (S_ - 1) ? (S_ - 1) : (st);                            \
    int sg_ = dir ? (S_ - 1 - tt_) : tt_;                                   \
    const float* xp_ = xgi + ((size_t)dir * 2048 + sg_ * 64 + b) * 384 + g0;\
    Vr[slot] = *(const float4*)&xp_[0];                                     \
    Vz[slot] = *(const float4*)&xp_[128];                                   \
    Vn[slot] = *(const float4*)&xp_[256];                                   \
  } while (0)

  GLOAD_S(0, 0);
  GLOAD_S(1, 1);
  GLOAD_S(2, 2);

  int p = 0;
  for (int it = 0; it < S_ / 4; ++it) {
#pragma unroll
    for (int j = 0; j < 4; ++j) {
      const int step = it * 4 + j;
      const int sI = dir ? (S_ - 1 - step) : step;
      GLOAD_S((j + 3) & 3, step + 3);

      s8v bfr[4];
      for (int kf = 0; kf < 4; ++kf)
        bfr[kf] = *(const s8v*)&hb[p][ln * 136 + kf * 32 + q * 8];
      f32x4 c0 = {0.f, 0.f, 0.f, 0.f}, c1 = c0, c2 = c0;
      for (int kf = 0; kf < 4; ++kf) {
        c0 = mfma16(af[0][kf], bfr[kf], c0);
        c1 = mfma16(af[1][kf], bfr[kf], c1);
        c2 = mfma16(af[2][kf], bfr[kf], c2);
      }
      const float irv[4] = {Vr[j].x, Vr[j].y, Vr[j].z, Vr[j].w};
      const float izv[4] = {Vz[j].x, Vz[j].y, Vz[j].z, Vz[j].w};
      const float inv[4] = {Vn[j].x, Vn[j].y, Vn[j].z, Vn[j].w};
      unsigned short hnb[4];
      for (int r = 0; r < 4; ++r) {
        float rr = fsigm(irv[r] + c0[r]);
        float zz = fsigm(izv[r] + c1[r]);
        float nn = ftanh(inv[r] + rr * (c2[r] + hbn[r]));
        float hv = zz * (h[r] - nn) + nn;
        h[r] = hv;
        hnb[r] = f2b(hv);
      }
      ushort4 hv4; hv4.x = hnb[0]; hv4.y = hnb[1]; hv4.z = hnb[2]; hv4.w = hnb[3];
      *(ushort4*)&hb[p ^ 1][ln * 136 + g0] = hv4;
      float4 of4; of4.x = h[0]; of4.y = h[1]; of4.z = h[2]; of4.w = h[3];
      *(float4*)&io2[((size_t)(sI * 64 + b)) * 256 + dir * 128 + g0] = of4;
      lds_barrier();
      p ^= 1;
    }
  }
#undef GLOAD_S
}

// ============================================================================
// K6: a2[s*64+b] = proj_inter . tanh(io2 @ W_W_inter + b_inter)  (no softmax)
// ============================================================================
__global__ __launch_bounds__(256) void k_attn_i(
    const float* __restrict__ io2,
    const float* __restrict__ wwI,   // [256][256] fp32 h-major
    const float* __restrict__ bI,
    const float* __restrict__ projI,
    float* __restrict__ a2)          // [2048]
{
  const int bid = blockIdx.x, tid = threadIdx.x;
  const int r0 = bid * 8;
  __shared__ float iol[8 * 256];
  __shared__ float red[4 * 8];
  for (int i = 0; i < 8; ++i) iol[i * 256 + tid] = io2[(size_t)(r0 + i) * 256 + tid];
  __syncthreads();
  float acc[8];
  for (int i = 0; i < 8; ++i) acc[i] = 0.f;
  for (int hh = 0; hh < 256; ++hh) {
    const float wv = wwI[hh * 256 + tid];
    for (int i = 0; i < 8; ++i) acc[i] += wv * iol[i * 256 + hh];
  }
  const float bb = bI[tid], pp = projI[tid];
  float p[8];
  for (int i = 0; i < 8; ++i) p[i] = pp * ftanh(acc[i] + bb);
  for (int d = 1; d < 64; d <<= 1)
    for (int i = 0; i < 8; ++i) p[i] += __shfl_xor(p[i], d);
  const int w = tid >> 6, l = tid & 63;
  if (l == 0)
    for (int i = 0; i < 8; ++i) red[w * 8 + i] = p[i];
  __syncthreads();
  if (tid < 8) a2[r0 + tid] = red[tid] + red[8 + tid] + red[16 + tid] + red[24 + tid];
}

// ============================================================================
// K7: doc_vec = sum_s a2 * io2 ; out = doc @ W_final^T + b_final  (fp32 out)
// ============================================================================
__global__ __launch_bounds__(256) void k_final(
    const float* __restrict__ a2,
    const float* __restrict__ io2,
    const float* __restrict__ wf,    // [5][256] fp32
    const float* __restrict__ bfi,   // [5] fp32
    float* __restrict__ out)         // [64][5] fp32
{
  const int b = blockIdx.x, tid = threadIdx.x;
  __shared__ float av[S_];
  __shared__ float dv[256];
  __shared__ float red[4];
  if (tid < S_) av[tid] = a2[tid * 64 + b];
  __syncthreads();
  float acc = 0.f;
  for (int s = 0; s < S_; ++s) acc += av[s] * io2[((size_t)(s * 64 + b)) * 256 + tid];
  dv[tid] = acc;
  __syncthreads();
  for (int c = 0; c < C_; ++c) {
    float pv = wf[c * 256 + tid] * dv[tid];
    for (int d = 1; d < 64; d <<= 1) pv += __shfl_xor(pv, d);
    const int w = tid >> 6, l = tid & 63;
    if (l == 0) red[w] = pv;
    __syncthreads();
    if (tid == 0)
      out[b * C_ + c] = red[0] + red[1] + red[2] + red[3] + bfi[c];
    __syncthreads();
  }
}

// ============================================================================
extern "C" void kernel_launch(void* const* d_in, const int* in_sizes, int n_in,
                              void* d_out, int out_size, void* d_ws, size_t ws_size,
                              hipStream_t stream) {
  (void)in_sizes; (void)n_in; (void)out_size; (void)ws_size;
  const int*   tokens = (const int*)d_in[0];
  const float* emb    = (const float*)d_in[1];
  const float* wih_a  = (const float*)d_in[2];
  const float* whh_a  = (const float*)d_in[3];
  const float* bih_a  = (const float*)d_in[4];
  const float* bhh_a  = (const float*)d_in[5];
  const float* ww_a   = (const float*)d_in[6];
  const float* b_a    = (const float*)d_in[7];
  const float* proj_a = (const float*)d_in[8];
  const float* wih_i  = (const float*)d_in[9];
  const float* whh_i  = (const float*)d_in[10];
  const float* bih_i  = (const float*)d_in[11];
  const float* bhh_i  = (const float*)d_in[12];
  const float* ww_i   = (const float*)d_in[13];
  const float* b_i    = (const float*)d_in[14];
  const float* proj_i = (const float*)d_in[15];
  const float* w_fin  = (const float*)d_in[16];
  const float* b_fin  = (const float*)d_in[17];

  char* ws = (char*)d_ws;
  unsigned short* gtab = (unsigned short*)(ws + 0);          // 49,152,000 B
  unsigned short* wta  = (unsigned short*)(ws + 49152000);   //    131,072 B
  unsigned short* iout = (unsigned short*)(ws + 49283072);   // 67,108,864 B
  unsigned short* wib  = (unsigned short*)(ws + 116391936);  //    393,216 B
  float* xgi = (float*)(ws + 119537664);                     //  6,291,456 B
  float* io2 = (float*)(ws + 125829120);                     //  2,097,152 B
  float* a2  = (float*)(ws + 127926272);                     //      8,192 B

  k_gtab<<<508, 256, 0, stream>>>(emb, wih_a, bih_a, bhh_a, ww_a, wih_i,
                                  gtab, wta, wib);
  k_intra<<<512, 512, 0, stream>>>(tokens, gtab, whh_a, bhh_a, iout);
  k_attn<<<256, 512, 0, stream>>>(iout, wta, b_a, proj_a, wib, bih_i, bhh_i, xgi);
  k_inter<<<8, 512, 0, stream>>>(xgi, whh_i, bhh_i, io2);
  k_attn_i<<<256, 256, 0, stream>>>(io2, ww_i, b_i, proj_i, a2);
  k_final<<<64, 256, 0, stream>>>(a2, io2, w_fin, b_fin, (float*)d_out);
}

// Round 6
// 320.542 us; speedup vs baseline: 1.0559x; 1.0559x over previous
//
#include <hip/hip_runtime.h>

// Problem dims
#define S_ 32
#define T_ 64
#define B_ 64
#define V_ 32000
#define E_ 128
#define H_ 128
#define G_ 128
#define C_ 5

typedef short s8v __attribute__((ext_vector_type(8)));   // 8 bf16 payload
typedef __bf16 b8v __attribute__((ext_vector_type(8)));
typedef float f32x4 __attribute__((ext_vector_type(4)));

// --- MFMA wrapper: tolerate either builtin operand signature (short8 or bf16x8)
template <typename V>
__device__ inline auto mfma_sel(V a, V b, f32x4 c, int)
    -> decltype(__builtin_amdgcn_mfma_f32_16x16x32_bf16(a, b, c, 0, 0, 0)) {
  return __builtin_amdgcn_mfma_f32_16x16x32_bf16(a, b, c, 0, 0, 0);
}
template <typename V>
__device__ inline f32x4 mfma_sel(V a, V b, f32x4 c, long) {
  return __builtin_amdgcn_mfma_f32_16x16x32_bf16(
      __builtin_bit_cast(b8v, a), __builtin_bit_cast(b8v, b), c, 0, 0, 0);
}
__device__ inline f32x4 mfma16(s8v a, s8v b, f32x4 c) { return mfma_sel(a, b, c, 0); }

__device__ inline float b2f(unsigned short u) {
  union { unsigned int i; float f; } v; v.i = ((unsigned int)u) << 16; return v.f;
}
// round-to-nearest (ties away) — 2 instr; RNE tie diff is <=1ulp, irrelevant at 2% tol
__device__ inline unsigned short f2b(float f) {
  union { float f; unsigned int i; } v; v.f = f;
  return (unsigned short)((v.i + 0x8000u) >> 16);
}
// full-RNE for the precomputed tables (cheap there, done once per element)
__device__ inline unsigned short f2b_rne(float f) {
  union { float f; unsigned int i; } v; v.f = f;
  unsigned int r = (v.i + 0x7fffu + ((v.i >> 16) & 1u)) >> 16;
  return (unsigned short)r;
}
__device__ inline s8v cvt8(const float* p) {
  const float4 a = *(const float4*)p;
  const float4 b = *(const float4*)(p + 4);
  s8v r;
  r[0] = (short)f2b_rne(a.x); r[1] = (short)f2b_rne(a.y);
  r[2] = (short)f2b_rne(a.z); r[3] = (short)f2b_rne(a.w);
  r[4] = (short)f2b_rne(b.x); r[5] = (short)f2b_rne(b.y);
  r[6] = (short)f2b_rne(b.z); r[7] = (short)f2b_rne(b.w);
  return r;
}
// division-free activations: raw v_rcp_f32 + v_exp_f32 (1 instr each).
__device__ inline float fsigm(float x) {
  return __builtin_amdgcn_rcpf(1.f + __builtin_amdgcn_exp2f(-1.44269504f * x));
}
__device__ inline float ftanh(float x) {
  return 1.f - 2.f * __builtin_amdgcn_rcpf(1.f + __builtin_amdgcn_exp2f(2.88539008f * x));
}

// LDS-only barrier: waits LDS ops, does NOT drain vmcnt — global loads issued
// before this stay in flight across it (cross-wave data here is LDS-only).
__device__ inline void lds_barrier() {
  asm volatile("s_waitcnt lgkmcnt(0)\n\ts_barrier" ::: "memory");
}

// ============================================================================
// K1: gtab[v][c] = sum_e emb[v][e]*Wih_intra[c][e] + bih[c] (+bhh[c] folded for
// r,z gates). MFMA GEMM: 500 blocks own a 64-row emb tile and iterate ALL 6
// N-chunks. Blocks 500..503: transpose W_W_intra. Blocks 504..507: convert
// Wih_inter fp32 -> bf16 (for the fused xgi MFMA in k_attn).
// ============================================================================
__global__ __launch_bounds__(256) void k_gtab(
    const float* __restrict__ emb,
    const float* __restrict__ wih,   // [768][128] fp32
    const float* __restrict__ bih,   // [768] fp32
    const float* __restrict__ bhh,   // [768] fp32 (r,z folded; n NOT)
    const float* __restrict__ wwi,   // [256][256] fp32 (h-major)
    const float* __restrict__ wihI,  // [768][256] fp32 (inter input weights)
    unsigned short* __restrict__ gtab,   // [V][768] bf16
    unsigned short* __restrict__ wta,    // [256][256] bf16 (n-major)
    unsigned short* __restrict__ wib)    // [768][256] bf16
{
  __shared__ __align__(16) unsigned short smem[64 * 264];  // union: alds / tbuf
  const int bid = blockIdx.x, tid = threadIdx.x;
  if (bid >= 504) {  // wihI fp32 -> bf16, 4 blocks
    const int cb = bid - 504;
    for (int i = 0; i < 48; ++i) {
      int e4 = cb * 12288 + i * 256 + tid;  // float4 index
      float4 v = *(const float4*)&wihI[(size_t)e4 * 4];
      ushort4 u;
      u.x = f2b_rne(v.x); u.y = f2b_rne(v.y); u.z = f2b_rne(v.z); u.w = f2b_rne(v.w);
      *(ushort4*)&wib[(size_t)e4 * 4] = u;
    }
    return;
  }
  if (bid >= 500) {  // LDS-tiled transpose, 4 blocks x 64 n-rows
    const int n0 = (bid - 500) * 64;
    for (int i = 0; i < 64; ++i) {
      int cid = i * 256 + tid;
      int k = cid >> 6, nl = cid & 63;
      smem[nl * 264 + k] = f2b_rne(wwi[k * 256 + n0 + nl]);  // coalesced read
    }
    __syncthreads();
    for (int i = 0; i < 8; ++i) {
      int cid = i * 256 + tid;
      int nl = cid >> 5, k8 = cid & 31;
      *(int4*)&wta[(size_t)(n0 + nl) * 256 + k8 * 8] =
          *(const int4*)&smem[nl * 264 + k8 * 8];            // coalesced write
    }
    return;
  }
  const int vbase = bid * 64;
  for (int i = 0; i < 8; ++i) {
    int cid = i * 256 + tid;           // 2048 chunks of 4 floats
    int row = cid >> 5, kc = cid & 31;
    float4 v = *(const float4*)&emb[(size_t)(vbase + row) * 128 + kc * 4];
    ushort4 u;
    u.x = f2b_rne(v.x); u.y = f2b_rne(v.y); u.z = f2b_rne(v.z); u.w = f2b_rne(v.w);
    *(ushort4*)&smem[row * 136 + kc * 4] = u;
  }
  __syncthreads();
  const int w = tid >> 6, l = tid & 63, q = l >> 4, ln = l & 15;
  // hoist all A fragments (16 s8v = 64 VGPR) — reused across 6 N-chunks
  s8v af[4][4];
  for (int mt = 0; mt < 4; ++mt)
    for (int kf = 0; kf < 4; ++kf)
      af[mt][kf] = *(const s8v*)&smem[(mt * 16 + ln) * 136 + kf * 32 + q * 8];
  for (int nchunk = 0; nchunk < 6; ++nchunk) {
    const int nbase = nchunk * 128;
    s8v bf[2][4];
    float bias[2];
    for (int nt = 0; nt < 2; ++nt) {
      int c = nbase + (w * 2 + nt) * 16 + ln;
      int g = (c < 384) ? c : (c - 384);       // gate index within direction
      bias[nt] = bih[c] + (g < 256 ? bhh[c] : 0.f);  // fold r,z recurrent bias
      for (int kf = 0; kf < 4; ++kf)
        bf[nt][kf] = cvt8(&wih[(size_t)c * 128 + kf * 32 + q * 8]);
    }
    for (int mt = 0; mt < 4; ++mt) {
      for (int nt = 0; nt < 2; ++nt) {
        f32x4 acc = {0.f, 0.f, 0.f, 0.f};
        for (int kf = 0; kf < 4; ++kf) acc = mfma16(af[mt][kf], bf[nt][kf], acc);
        const int col = nbase + (w * 2 + nt) * 16 + ln;
        for (int r = 0; r < 4; ++r) {
          const int row = vbase + mt * 16 + q * 4 + r;
          gtab[(size_t)row * 768 + col] = f2b_rne(acc[r] + bias[nt]);
        }
      }
    }
  }
}

// ============================================================================
// K2: intra biGRU. Grid 256 = (s, dir, b-quad of 16), 1 block/CU (R4's
// 2-chains/CU co-residency measured 1.74x slower per chain — reverted).
// 4 waves x 64 (256 threads); each wave owns 32 gate-dims (2 halves of 16).
// Halves block LDS-read ops per step, syncs 4 waves instead of 8, and puts
// 1 wave/SIMD (no intra-SIMD issue round-robin on the critical path).
// Depth-3 token-gather pipeline (4 static register slots, x4 unroll).
// ============================================================================
__global__ __launch_bounds__(256) void k_intra(
    const int* __restrict__ tokens,
    const unsigned short* __restrict__ gtab,  // bf16, r/z biases folded
    const float* __restrict__ whh,            // [2][384][128] fp32
    const float* __restrict__ bhh,            // [2][384] fp32 (n-gate used)
    unsigned short* __restrict__ iout)        // [S*T*B][256] bf16 internal
{
  const int bid = blockIdx.x;
  const int s = bid >> 3, dir = (bid >> 2) & 1, bq = bid & 3;
  const int bbase = bq * 16;
  const int tid = threadIdx.x;
  const int w = tid >> 6, l = tid & 63, q = l >> 4, ln = l & 15;
  const int gb0 = w * 32;                 // this wave's 32 gate-dims
  const int g00 = gb0 + q * 4;            // half 0 per-lane dims
  const int g01 = gb0 + 16 + q * 4;       // half 1 per-lane dims

  __shared__ __align__(16) unsigned short hb[2][16 * 136];
  __shared__ int tokl[T_ * 16];

  for (int i = tid; i < 2 * 16 * 136; i += 256) ((unsigned short*)hb)[i] = 0;
  for (int i = tid; i < T_ * 16; i += 256) {
    int t = i >> 4, bl = i & 15;
    tokl[i] = tokens[(s * T_ + t) * B_ + bbase + bl] * 768 + dir * 384;
  }

  s8v af[3][2][4];
  float hbn[2][4];
  const float* whd = whh + (size_t)dir * (384 * 128);
  const float* bhd = bhh + dir * 384;
#pragma unroll
  for (int g3 = 0; g3 < 3; ++g3)
#pragma unroll
    for (int hf = 0; hf < 2; ++hf)
      for (int kf = 0; kf < 4; ++kf)
        af[g3][hf][kf] =
            cvt8(&whd[(size_t)(g3 * 128 + gb0 + hf * 16 + ln) * 128 + kf * 32 + q * 8]);
#pragma unroll
  for (int hf = 0; hf < 2; ++hf)
    for (int r = 0; r < 4; ++r)
      hbn[hf][r] = bhd[256 + gb0 + hf * 16 + q * 4 + r];  // n-gate only
  float h[2][4] = {{0.f, 0.f, 0.f, 0.f}, {0.f, 0.f, 0.f, 0.f}};
  const int b = bbase + ln;
  __syncthreads();

  // --- depth-3 gather pipeline, 4 static register slots, both halves ---
  ushort4 Xr[2][4], Xz[2][4], Xn[2][4];
#define GLOAD_I(slot, st)                                                   \
  do {                                                                      \
    int tt_ = (st) > (T_ - 1) ? (T_ - 1) : (st);                            \
    int tg_ = dir ? (T_ - 1 - tt_) : tt_;                                   \
    const unsigned short* gp_ = gtab + (size_t)(tokl[tg_ * 16 + ln]);       \
    Xr[0][slot] = *(const ushort4*)&gp_[g00];                               \
    Xz[0][slot] = *(const ushort4*)&gp_[128 + g00];                         \
    Xn[0][slot] = *(const ushort4*)&gp_[256 + g00];                         \
    Xr[1][slot] = *(const ushort4*)&gp_[g01];                               \
    Xz[1][slot] = *(const ushort4*)&gp_[128 + g01];                         \
    Xn[1][slot] = *(const ushort4*)&gp_[256 + g01];                         \
  } while (0)

  GLOAD_I(0, 0);
  GLOAD_I(1, 1);
  GLOAD_I(2, 2);

  int p = 0;
  for (int it = 0; it < T_ / 4; ++it) {
#pragma unroll
    for (int j = 0; j < 4; ++j) {
      const int step = it * 4 + j;
      const int t = dir ? (T_ - 1 - step) : step;
      GLOAD_I((j + 3) & 3, step + 3);   // prefetch 3 steps ahead

      s8v bfr[4];
      for (int kf = 0; kf < 4; ++kf)
        bfr[kf] = *(const s8v*)&hb[p][ln * 136 + kf * 32 + q * 8];
      f32x4 c[3][2];
#pragma unroll
      for (int g3 = 0; g3 < 3; ++g3)
#pragma unroll
        for (int hf = 0; hf < 2; ++hf) {
          f32x4 z = {0.f, 0.f, 0.f, 0.f};
          c[g3][hf] = z;
        }
      for (int kf = 0; kf < 4; ++kf) {
#pragma unroll
        for (int g3 = 0; g3 < 3; ++g3)
#pragma unroll
          for (int hf = 0; hf < 2; ++hf)
            c[g3][hf] = mfma16(af[g3][hf][kf], bfr[kf], c[g3][hf]);
      }

      const size_t rowbase = ((size_t)(s * T_ + t) * B_ + b) * 256 + dir * 128;
#pragma unroll
      for (int hf = 0; hf < 2; ++hf) {
        const unsigned short* xrp = (const unsigned short*)&Xr[hf][j];
        const unsigned short* xzp = (const unsigned short*)&Xz[hf][j];
        const unsigned short* xnp = (const unsigned short*)&Xn[hf][j];
        unsigned short hnb[4];
        for (int r = 0; r < 4; ++r) {
          float rr = fsigm(b2f(xrp[r]) + c[0][hf][r]);                 // bhh_r folded
          float zz = fsigm(b2f(xzp[r]) + c[1][hf][r]);                 // bhh_z folded
          float nn = ftanh(b2f(xnp[r]) + rr * (c[2][hf][r] + hbn[hf][r]));
          float hv = zz * (h[hf][r] - nn) + nn;
          h[hf][r] = hv;
          hnb[r] = f2b(hv);
        }
        ushort4 hv4; hv4.x = hnb[0]; hv4.y = hnb[1]; hv4.z = hnb[2]; hv4.w = hnb[3];
        *(ushort4*)&hb[p ^ 1][ln * 136 + gb0 + hf * 16 + q * 4] = hv4;
        *(ushort4*)&iout[rowbase + gb0 + hf * 16 + q * 4] = hv4;
      }
      lds_barrier();
      p ^= 1;
    }
  }
#undef GLOAD_I
}

// ============================================================================
// K3 (fused attn + xgi): one pass over iout. Grid 256 = (s, b-group of 8).
// Full W_W_intra (128 KB) in LDS; flash-style single iout read; cross-wave
// merge through the freed W region; THEN the inter input-gate GEMM
// (xgi = sv @ WihI^T + biases) fused on the block's 8 sv rows via bf16 MFMA.
// ============================================================================
__global__ __launch_bounds__(512, 1) void k_attn(
    const unsigned short* __restrict__ iout,  // bf16 internal
    const unsigned short* __restrict__ wta,   // bf16 [256][256] n-major
    const float* __restrict__ bint,           // [256] fp32
    const float* __restrict__ proj,           // [256] fp32
    const unsigned short* __restrict__ wib,   // bf16 [768][256] (WihI)
    const float* __restrict__ bihI,           // [768] fp32
    const float* __restrict__ bhhI,           // [768] fp32
    float* __restrict__ xgi)                  // [2][2048][384] fp32
{
  __shared__ __align__(16) unsigned short wlds[256 * 256];  // 128 KB, XOR-swizzled
  __shared__ float lgbuf[8][16];
  __shared__ float lbuf[8][8];
  const int tid = threadIdx.x, bid = blockIdx.x;
  const int s = bid >> 3, b0 = (bid & 7) * 8;
  // stage full W (both halves)
  for (int i = 0; i < 16; ++i) {
    int cid = i * 512 + tid;          // 8192 16B chunks
    int n = cid >> 5, kc = cid & 31;
    *(int4*)&wlds[n * 256 + ((kc ^ (n & 15)) << 3)] =
        *(const int4*)&wta[(size_t)n * 256 + kc * 8];
  }
  const int w = tid >> 6, l = tid & 63, q = l >> 4, ln = l & 15;
  float bbv[16], ppv[16];
  for (int nt = 0; nt < 16; ++nt) {     // per-lane bias/proj for its n-cols
    bbv[nt] = bint[nt * 16 + ln];
    ppv[nt] = proj[nt * 16 + ln];
  }
  __syncthreads();

  float O[8][8];                        // [kf][j] weighted-sum accumulator
  for (int kf = 0; kf < 8; ++kf)
    for (int j = 0; j < 8; ++j) O[kf][j] = 0.f;
  float l_acc = 0.f;

  for (int tile = 0; tile < 4; ++tile) {  // wave w owns t = 8w .. 8w+7
    const int t = (w * 4 + tile) * 2 + (ln >> 3);
    const size_t row = (size_t)((s * T_ + t) * B_ + b0 + (ln & 7));
    s8v af[8];
    for (int kf = 0; kf < 8; ++kf)
      af[kf] = *(const s8v*)&iout[row * 256 + kf * 32 + q * 8];
    float p0 = 0.f, p1 = 0.f, p2 = 0.f, p3 = 0.f;
    for (int nt = 0; nt < 16; ++nt) {
      f32x4 c = {0.f, 0.f, 0.f, 0.f};
      for (int kf = 0; kf < 8; ++kf) {
        s8v bf = *(const s8v*)&wlds[(nt * 16 + ln) * 256 + (((kf * 4 + q) ^ ln) << 3)];
        c = mfma16(af[kf], bf, c);
      }
      p0 += ppv[nt] * ftanh(c[0] + bbv[nt]);
      p1 += ppv[nt] * ftanh(c[1] + bbv[nt]);
      p2 += ppv[nt] * ftanh(c[2] + bbv[nt]);
      p3 += ppv[nt] * ftanh(c[3] + bbv[nt]);
    }
    for (int d = 1; d < 16; d <<= 1) {   // reduce over n-col lanes
      p0 += __shfl_xor(p0, d); p1 += __shfl_xor(p1, d);
      p2 += __shfl_xor(p2, d); p3 += __shfl_xor(p3, d);
    }
    // remap logits (held per D-row q*4+r) to A-row layout via same-wave LDS
    if (ln == 0) {
      lgbuf[w][q * 4 + 0] = p0; lgbuf[w][q * 4 + 1] = p1;
      lgbuf[w][q * 4 + 2] = p2; lgbuf[w][q * 4 + 3] = p3;
    }
    const float lg = lgbuf[w][ln];       // logit for THIS lane's (t,b) row
    const float e = __builtin_amdgcn_exp2f(1.44269504f * lg);
    l_acc += e;
    for (int kf = 0; kf < 8; ++kf)
      for (int j = 0; j < 8; ++j)
        O[kf][j] += e * b2f((unsigned short)af[kf][j]);
  }
  // merge t-pair lanes (ln, ln+8): same b, same dims
  l_acc += __shfl_xor(l_acc, 8);
  for (int kf = 0; kf < 8; ++kf)
    for (int j = 0; j < 8; ++j) O[kf][j] += __shfl_xor(O[kf][j], 8);
  __syncthreads();                       // everyone done reading wlds
  float* obuf = (float*)wlds;            // overlay [0..64K): [8 waves][8 b][256 d]
  unsigned short* svl = (unsigned short*)(((char*)wlds) + 65536);  // [16][264] bf16
  if (ln < 8) {
    const int base = w * 2048 + ln * 256 + q * 8;
    for (int kf = 0; kf < 8; ++kf) {
      float4 v0; v0.x = O[kf][0]; v0.y = O[kf][1]; v0.z = O[kf][2]; v0.w = O[kf][3];
      float4 v1; v1.x = O[kf][4]; v1.y = O[kf][5]; v1.z = O[kf][6]; v1.w = O[kf][7];
      *(float4*)&obuf[base + kf * 32]     = v0;
      *(float4*)&obuf[base + kf * 32 + 4] = v1;
    }
    if (q == 0) lbuf[w][ln] = l_acc;
  }
  // zero pad rows 8..15 of svl (A-operand padding for the M=8 GEMM)
  {
    ushort4 z4; z4.x = 0; z4.y = 0; z4.z = 0; z4.w = 0;
    int rr = 8 + (tid >> 6), cc = (tid & 63) * 4;  // 8 rows x 256 cols, pad ignored
    *(ushort4*)&svl[rr * 264 + cc] = z4;
  }
  __syncthreads();
  // deterministic 8-way reduce + softmax normalize -> sv (bf16, into svl)
  const int idx = tid * 4;               // 2048 outputs / 512 threads
  const int bb_ = idx >> 8;
  float4 acc; acc.x = 0.f; acc.y = 0.f; acc.z = 0.f; acc.w = 0.f;
  float lsum = 0.f;
  for (int w8 = 0; w8 < 8; ++w8) {
    const float4 v = *(const float4*)&obuf[w8 * 2048 + idx];
    acc.x += v.x; acc.y += v.y; acc.z += v.z; acc.w += v.w;
    lsum += lbuf[w8][bb_];
  }
  const float inv = __builtin_amdgcn_rcpf(lsum);
  ushort4 u;
  u.x = f2b_rne(acc.x * inv); u.y = f2b_rne(acc.y * inv);
  u.z = f2b_rne(acc.z * inv); u.w = f2b_rne(acc.w * inv);
  *(ushort4*)&svl[bb_ * 264 + (idx & 255)] = u;
  __syncthreads();
  // ---- fused xgi GEMM: out[m=0..7][c=0..767] = sv . WihI[c] + bias ----
  s8v afx[8];
  for (int kf = 0; kf < 8; ++kf)
    afx[kf] = *(const s8v*)&svl[ln * 264 + kf * 32 + q * 8];
  for (int nt = 0; nt < 6; ++nt) {
    const int c = w * 96 + nt * 16 + ln;  // col 0..767
    const int dirI = (c >= 384) ? 1 : 0;
    const int g = c - dirI * 384;
    const float biasx = bihI[c] + (g < 256 ? bhhI[c] : 0.f);  // fold r,z
    f32x4 cacc = {0.f, 0.f, 0.f, 0.f};
    for (int kf = 0; kf < 8; ++kf) {
      s8v bfx = *(const s8v*)&wib[(size_t)c * 256 + kf * 32 + q * 8];
      cacc = mfma16(afx[kf], bfx, cacc);
    }
    if (q < 2) {                          // rows 0..7 are real sv rows
      for (int r = 0; r < 4; ++r) {
        const int m = q * 4 + r;
        xgi[((size_t)dirI * 2048 + s * B_ + b0 + m) * 384 + g] = cacc[r] + biasx;
      }
    }
  }
}

// ============================================================================
// K5: inter biGRU. Grid 8 = (dir, b-quad of 16). Depth-3 pipelined gate loads.
// ============================================================================
__global__ __launch_bounds__(512) void k_inter(
    const float* __restrict__ xgi,   // r,z biases folded
    const float* __restrict__ whh,   // [2][384][128] fp32
    const float* __restrict__ bhh,   // [2][384] fp32 (n-gate used)
    float* __restrict__ io2)         // [S*B][256] fp32
{
  const int bid = blockIdx.x;
  const int dir = bid >> 2, bq = bid & 3, bbase = bq * 16;
  const int tid = threadIdx.x;
  const int w = tid >> 6, l = tid & 63, q = l >> 4, ln = l & 15;
  const int gbase = w * 16, g0 = gbase + q * 4;
  __shared__ __align__(16) unsigned short hb[2][16 * 136];
  for (int i = tid; i < 2 * 16 * 136; i += 512) ((unsigned short*)hb)[i] = 0;
  s8v af[3][4];
  float hbn[4];
  const float* whd = whh + (size_t)dir * (384 * 128);
  const float* bhd = bhh + dir * 384;
  for (int g3 = 0; g3 < 3; ++g3) {
    const int R = g3 * 128 + gbase;
    for (int kf = 0; kf < 4; ++kf)
      af[g3][kf] = cvt8(&whd[(size_t)(R + ln) * 128 + kf * 32 + q * 8]);
  }
  for (int r = 0; r < 4; ++r) hbn[r] = bhd[256 + gbase + q * 4 + r];
  float h[4] = {0.f, 0.f, 0.f, 0.f};
  const int b = bbase + ln;
  __syncthreads();

  float4 Vr[4], Vz[4], Vn[4];
#define GLOAD_S(slot, st)                                                   \
  do {                                                                      \
    int tt_ = (st) > (S_ - 1) ? (S_ - 1) : (st);                            \
    int sg_ = dir ? (S_ - 1 - tt_) : tt_;                                   \
    const float* xp_ = xgi + ((size_t)dir * 2048 + sg_ * 64 + b) * 384 + g0;\
    Vr[slot] = *(const float4*)&xp_[0];                                     \
    Vz[slot] = *(const float4*)&xp_[128];                                   \
    Vn[slot] = *(const float4*)&xp_[256];                                   \
  } while (0)

  GLOAD_S(0, 0);
  GLOAD_S(1, 1);
  GLOAD_S(2, 2);

  int p = 0;
  for (int it = 0; it < S_ / 4; ++it) {
#pragma unroll
    for (int j = 0; j < 4; ++j) {
      const int step = it * 4 + j;
      const int sI = dir ? (S_ - 1 - step) : step;
      GLOAD_S((j + 3) & 3, step + 3);

      s8v bfr[4];
      for (int kf = 0; kf < 4; ++kf)
        bfr[kf] = *(const s8v*)&hb[p][ln * 136 + kf * 32 + q * 8];
      f32x4 c0 = {0.f, 0.f, 0.f, 0.f}, c1 = c0, c2 = c0;
      for (int kf = 0; kf < 4; ++kf) {
        c0 = mfma16(af[0][kf], bfr[kf], c0);
        c1 = mfma16(af[1][kf], bfr[kf], c1);
        c2 = mfma16(af[2][kf], bfr[kf], c2);
      }
      const float irv[4] = {Vr[j].x, Vr[j].y, Vr[j].z, Vr[j].w};
      const float izv[4] = {Vz[j].x, Vz[j].y, Vz[j].z, Vz[j].w};
      const float inv[4] = {Vn[j].x, Vn[j].y, Vn[j].z, Vn[j].w};
      unsigned short hnb[4];
      for (int r = 0; r < 4; ++r) {
        float rr = fsigm(irv[r] + c0[r]);
        float zz = fsigm(izv[r] + c1[r]);
        float nn = ftanh(inv[r] + rr * (c2[r] + hbn[r]));
        float hv = zz * (h[r] - nn) + nn;
        h[r] = hv;
        hnb[r] = f2b(hv);
      }
      ushort4 hv4; hv4.x = hnb[0]; hv4.y = hnb[1]; hv4.z = hnb[2]; hv4.w = hnb[3];
      *(ushort4*)&hb[p ^ 1][ln * 136 + g0] = hv4;
      float4 of4; of4.x = h[0]; of4.y = h[1]; of4.z = h[2]; of4.w = h[3];
      *(float4*)&io2[((size_t)(sI * 64 + b)) * 256 + dir * 128 + g0] = of4;
      lds_barrier();
      p ^= 1;
    }
  }
#undef GLOAD_S
}

// ============================================================================
// K6 (merged tail): per-b block computes a2[s] = projI . tanh(io2 @ wwI + bI)
// for its 32 s, then doc_vec = sum_s a2*io2, then out = doc @ Wf^T + bf.
// Replaces the old k_attn_i + k_final pair (saves one launch + a2 roundtrip).
// ============================================================================
__global__ __launch_bounds__(512) void k_tail(
    const float* __restrict__ io2,   // [S*B][256] fp32
    const float* __restrict__ wwI,   // [256][256] fp32 h-major
    const float* __restrict__ bI,    // [256]
    const float* __restrict__ projI, // [256]
    const float* __restrict__ wf,    // [5][256]
    const float* __restrict__ bfi,   // [5]
    float* __restrict__ out)         // [64][5]
{
  const int b = blockIdx.x, tid = threadIdx.x;
  __shared__ __align__(16) float iol[32][256];   // 32 KB
  __shared__ float pr[8][16];
  __shared__ float a2s[32];
  __shared__ float red2[4];
  for (int i = tid; i < 32 * 256; i += 512) {
    int ss = i >> 8, d = i & 255;
    iol[ss][d] = io2[(size_t)(ss * 64 + b) * 256 + d];
  }
  __syncthreads();
  // ---- attn_i: thread (k, g): g picks s-half; acc over 16 s rows ----
  const int k = tid & 255, g = tid >> 8;
  float acc[16];
  for (int i = 0; i < 16; ++i) acc[i] = 0.f;
  for (int h4 = 0; h4 < 64; ++h4) {
    const float w0 = wwI[(h4 * 4 + 0) * 256 + k];
    const float w1 = wwI[(h4 * 4 + 1) * 256 + k];
    const float w2 = wwI[(h4 * 4 + 2) * 256 + k];
    const float w3 = wwI[(h4 * 4 + 3) * 256 + k];
    for (int i = 0; i < 16; ++i) {
      const float4 v = *(const float4*)&iol[g * 16 + i][h4 * 4];  // LDS b128 broadcast
      acc[i] += w0 * v.x + w1 * v.y + w2 * v.z + w3 * v.w;
    }
  }
  const float bb = bI[k], pp = projI[k];
  float pv[16];
  for (int i = 0; i < 16; ++i) pv[i] = pp * ftanh(acc[i] + bb);
  for (int d = 1; d < 64; d <<= 1)
    for (int i = 0; i < 16; ++i) pv[i] += __shfl_xor(pv[i], d);
  if ((tid & 63) == 0)
    for (int i = 0; i < 16; ++i) pr[tid >> 6][i] = pv[i];
  __syncthreads();
  if (tid < 32) {
    const int g2 = tid >> 4, i2 = tid & 15;  // s = g2*16+i2
    a2s[g2 * 16 + i2] = pr[g2 * 4 + 0][i2] + pr[g2 * 4 + 1][i2] +
                        pr[g2 * 4 + 2][i2] + pr[g2 * 4 + 3][i2];
  }
  __syncthreads();
  // ---- final: dv[d] = sum_s a2s[s]*iol[s][d]; out = dv @ wf^T + bfi ----
  float dv = 0.f;
  if (tid < 256) {
    for (int ss = 0; ss < 32; ++ss) dv += a2s[ss] * iol[ss][tid];
  }
  for (int c = 0; c < C_; ++c) {
    float pvv = (tid < 256) ? wf[c * 256 + tid] * dv : 0.f;
    for (int d = 1; d < 64; d <<= 1) pvv += __shfl_xor(pvv, d);
    if (tid < 256 && (tid & 63) == 0) red2[tid >> 6] = pvv;
    __syncthreads();
    if (tid == 0)
      out[b * C_ + c] = red2[0] + red2[1] + red2[2] + red2[3] + bfi[c];
    __syncthreads();
  }
}

// ============================================================================
extern "C" void kernel_launch(void* const* d_in, const int* in_sizes, int n_in,
                              void* d_out, int out_size, void* d_ws, size_t ws_size,
                              hipStream_t stream) {
  (void)in_sizes; (void)n_in; (void)out_size; (void)ws_size;
  const int*   tokens = (const int*)d_in[0];
  const float* emb    = (const float*)d_in[1];
  const float* wih_a  = (const float*)d_in[2];
  const float* whh_a  = (const float*)d_in[3];
  const float* bih_a  = (const float*)d_in[4];
  const float* bhh_a  = (const float*)d_in[5];
  const float* ww_a   = (const float*)d_in[6];
  const float* b_a    = (const float*)d_in[7];
  const float* proj_a = (const float*)d_in[8];
  const float* wih_i  = (const float*)d_in[9];
  const float* whh_i  = (const float*)d_in[10];
  const float* bih_i  = (const float*)d_in[11];
  const float* bhh_i  = (const float*)d_in[12];
  const float* ww_i   = (const float*)d_in[13];
  const float* b_i    = (const float*)d_in[14];
  const float* proj_i = (const float*)d_in[15];
  const float* w_fin  = (const float*)d_in[16];
  const float* b_fin  = (const float*)d_in[17];

  char* ws = (char*)d_ws;
  unsigned short* gtab = (unsigned short*)(ws + 0);          // 49,152,000 B
  unsigned short* wta  = (unsigned short*)(ws + 49152000);   //    131,072 B
  unsigned short* iout = (unsigned short*)(ws + 49283072);   // 67,108,864 B
  unsigned short* wib  = (unsigned short*)(ws + 116391936);  //    393,216 B
  float* xgi = (float*)(ws + 119537664);                     //  6,291,456 B
  float* io2 = (float*)(ws + 125829120);                     //  2,097,152 B

  k_gtab<<<508, 256, 0, stream>>>(emb, wih_a, bih_a, bhh_a, ww_a, wih_i,
                                  gtab, wta, wib);
  k_intra<<<256, 256, 0, stream>>>(tokens, gtab, whh_a, bhh_a, iout);
  k_attn<<<256, 512, 0, stream>>>(iout, wta, b_a, proj_a, wib, bih_i, bhh_i, xgi);
  k_inter<<<8, 512, 0, stream>>>(xgi, whh_i, bhh_i, io2);
  k_tail<<<64, 512, 0, stream>>>(io2, ww_i, b_i, proj_i, w_fin, b_fin,
                                 (float*)d_out);
}

// Round 7
// 300.629 us; speedup vs baseline: 1.1259x; 1.0662x over previous
//
#include <hip/hip_runtime.h>

// Problem dims
#define S_ 32
#define T_ 64
#define B_ 64
#define V_ 32000
#define E_ 128
#define H_ 128
#define G_ 128
#define C_ 5

typedef short s8v __attribute__((ext_vector_type(8)));   // 8 bf16 payload
typedef __bf16 b8v __attribute__((ext_vector_type(8)));
typedef float f32x4 __attribute__((ext_vector_type(4)));

// --- MFMA wrapper: tolerate either builtin operand signature (short8 or bf16x8)
template <typename V>
__device__ inline auto mfma_sel(V a, V b, f32x4 c, int)
    -> decltype(__builtin_amdgcn_mfma_f32_16x16x32_bf16(a, b, c, 0, 0, 0)) {
  return __builtin_amdgcn_mfma_f32_16x16x32_bf16(a, b, c, 0, 0, 0);
}
template <typename V>
__device__ inline f32x4 mfma_sel(V a, V b, f32x4 c, long) {
  return __builtin_amdgcn_mfma_f32_16x16x32_bf16(
      __builtin_bit_cast(b8v, a), __builtin_bit_cast(b8v, b), c, 0, 0, 0);
}
__device__ inline f32x4 mfma16(s8v a, s8v b, f32x4 c) { return mfma_sel(a, b, c, 0); }

__device__ inline float b2f(unsigned short u) {
  union { unsigned int i; float f; } v; v.i = ((unsigned int)u) << 16; return v.f;
}
// round-to-nearest (ties away) — 2 instr; RNE tie diff is <=1ulp, irrelevant at 2% tol
__device__ inline unsigned short f2b(float f) {
  union { float f; unsigned int i; } v; v.f = f;
  return (unsigned short)((v.i + 0x8000u) >> 16);
}
// full-RNE for the precomputed tables (cheap there, done once per element)
__device__ inline unsigned short f2b_rne(float f) {
  union { float f; unsigned int i; } v; v.f = f;
  unsigned int r = (v.i + 0x7fffu + ((v.i >> 16) & 1u)) >> 16;
  return (unsigned short)r;
}
__device__ inline s8v cvt8(const float* p) {
  const float4 a = *(const float4*)p;
  const float4 b = *(const float4*)(p + 4);
  s8v r;
  r[0] = (short)f2b_rne(a.x); r[1] = (short)f2b_rne(a.y);
  r[2] = (short)f2b_rne(a.z); r[3] = (short)f2b_rne(a.w);
  r[4] = (short)f2b_rne(b.x); r[5] = (short)f2b_rne(b.y);
  r[6] = (short)f2b_rne(b.z); r[7] = (short)f2b_rne(b.w);
  return r;
}
// division-free activations: raw v_rcp_f32 + v_exp_f32 (1 instr each).
__device__ inline float fsigm(float x) {
  return __builtin_amdgcn_rcpf(1.f + __builtin_amdgcn_exp2f(-1.44269504f * x));
}
__device__ inline float ftanh(float x) {
  return 1.f - 2.f * __builtin_amdgcn_rcpf(1.f + __builtin_amdgcn_exp2f(2.88539008f * x));
}

// LDS-only barrier: waits LDS ops, does NOT drain vmcnt — global loads issued
// before this stay in flight across it (cross-wave data here is LDS-only).
__device__ inline void lds_barrier() {
  asm volatile("s_waitcnt lgkmcnt(0)\n\ts_barrier" ::: "memory");
}

// ============================================================================
// K1: gtab[v][c] = sum_e emb[v][e]*Wih_intra[c][e] + bih[c] (+bhh[c] folded for
// r,z gates). MFMA GEMM: 500 blocks own a 64-row emb tile and iterate ALL 6
// N-chunks. Blocks 500..503: transpose W_W_intra. Blocks 504..507: convert
// Wih_inter fp32 -> bf16 (for the fused xgi MFMA in k_attn).
// ============================================================================
__global__ __launch_bounds__(256) void k_gtab(
    const float* __restrict__ emb,
    const float* __restrict__ wih,   // [768][128] fp32
    const float* __restrict__ bih,   // [768] fp32
    const float* __restrict__ bhh,   // [768] fp32 (r,z folded; n NOT)
    const float* __restrict__ wwi,   // [256][256] fp32 (h-major)
    const float* __restrict__ wihI,  // [768][256] fp32 (inter input weights)
    unsigned short* __restrict__ gtab,   // [V][768] bf16
    unsigned short* __restrict__ wta,    // [256][256] bf16 (n-major)
    unsigned short* __restrict__ wib)    // [768][256] bf16
{
  __shared__ __align__(16) unsigned short smem[64 * 264];  // union: alds / tbuf
  const int bid = blockIdx.x, tid = threadIdx.x;
  if (bid >= 504) {  // wihI fp32 -> bf16, 4 blocks
    const int cb = bid - 504;
    for (int i = 0; i < 48; ++i) {
      int e4 = cb * 12288 + i * 256 + tid;  // float4 index
      float4 v = *(const float4*)&wihI[(size_t)e4 * 4];
      ushort4 u;
      u.x = f2b_rne(v.x); u.y = f2b_rne(v.y); u.z = f2b_rne(v.z); u.w = f2b_rne(v.w);
      *(ushort4*)&wib[(size_t)e4 * 4] = u;
    }
    return;
  }
  if (bid >= 500) {  // LDS-tiled transpose, 4 blocks x 64 n-rows
    const int n0 = (bid - 500) * 64;
    for (int i = 0; i < 64; ++i) {
      int cid = i * 256 + tid;
      int k = cid >> 6, nl = cid & 63;
      smem[nl * 264 + k] = f2b_rne(wwi[k * 256 + n0 + nl]);  // coalesced read
    }
    __syncthreads();
    for (int i = 0; i < 8; ++i) {
      int cid = i * 256 + tid;
      int nl = cid >> 5, k8 = cid & 31;
      *(int4*)&wta[(size_t)(n0 + nl) * 256 + k8 * 8] =
          *(const int4*)&smem[nl * 264 + k8 * 8];            // coalesced write
    }
    return;
  }
  const int vbase = bid * 64;
  for (int i = 0; i < 8; ++i) {
    int cid = i * 256 + tid;           // 2048 chunks of 4 floats
    int row = cid >> 5, kc = cid & 31;
    float4 v = *(const float4*)&emb[(size_t)(vbase + row) * 128 + kc * 4];
    ushort4 u;
    u.x = f2b_rne(v.x); u.y = f2b_rne(v.y); u.z = f2b_rne(v.z); u.w = f2b_rne(v.w);
    *(ushort4*)&smem[row * 136 + kc * 4] = u;
  }
  __syncthreads();
  const int w = tid >> 6, l = tid & 63, q = l >> 4, ln = l & 15;
  // hoist all A fragments (16 s8v = 64 VGPR) — reused across 6 N-chunks
  s8v af[4][4];
  for (int mt = 0; mt < 4; ++mt)
    for (int kf = 0; kf < 4; ++kf)
      af[mt][kf] = *(const s8v*)&smem[(mt * 16 + ln) * 136 + kf * 32 + q * 8];
  for (int nchunk = 0; nchunk < 6; ++nchunk) {
    const int nbase = nchunk * 128;
    s8v bf[2][4];
    float bias[2];
    for (int nt = 0; nt < 2; ++nt) {
      int c = nbase + (w * 2 + nt) * 16 + ln;
      int g = (c < 384) ? c : (c - 384);       // gate index within direction
      bias[nt] = bih[c] + (g < 256 ? bhh[c] : 0.f);  // fold r,z recurrent bias
      for (int kf = 0; kf < 4; ++kf)
        bf[nt][kf] = cvt8(&wih[(size_t)c * 128 + kf * 32 + q * 8]);
    }
    for (int mt = 0; mt < 4; ++mt) {
      for (int nt = 0; nt < 2; ++nt) {
        f32x4 acc = {0.f, 0.f, 0.f, 0.f};
        for (int kf = 0; kf < 4; ++kf) acc = mfma16(af[mt][kf], bf[nt][kf], acc);
        const int col = nbase + (w * 2 + nt) * 16 + ln;
        for (int r = 0; r < 4; ++r) {
          const int row = vbase + mt * 16 + q * 4 + r;
          gtab[(size_t)row * 768 + col] = f2b_rne(acc[r] + bias[nt]);
        }
      }
    }
  }
}

// ============================================================================
// K2: intra biGRU. Grid 256 = (s, dir, b-quad of 16), 8 waves (R3 structure).
// TRANSACTION-COUNT FIX: the per-step gtab gather previously fragmented into
// 384 x 32B transactions/step (the measured stall: depth-3 null, co-res
// negative => memory-pipe transaction-bound, not latency-bound). Now waves
// 0..5 fetch the 16 token rows as contiguous 16B/lane chunks (12 instrs ->
// 8 x 128B transactions each = 96/step), reg-staged into a double-buffered,
// row-padded LDS x-buffer (sync via the existing per-step barrier). The
// scattered iout stores (128 transactions/step) are replaced by a coalesced
// LDS->global copy of the previous step's h tile (32 transactions/step).
// ============================================================================
__global__ __launch_bounds__(512) void k_intra(
    const int* __restrict__ tokens,
    const unsigned short* __restrict__ gtab,  // bf16, r/z biases folded
    const float* __restrict__ whh,            // [2][384][128] fp32
    const float* __restrict__ bhh,            // [2][384] fp32 (n-gate used)
    unsigned short* __restrict__ iout)        // [S*T*B][256] bf16 internal
{
  const int bid = blockIdx.x;
  const int s = bid >> 3, dir = (bid >> 2) & 1, bq = bid & 3;
  const int bbase = bq * 16;
  const int tid = threadIdx.x;
  const int w = tid >> 6, l = tid & 63, q = l >> 4, ln = l & 15;
  const int gbase = w * 16, g0 = gbase + q * 4;

  __shared__ __align__(16) unsigned short hb[2][16 * 136];    // h state (dbuf)
  __shared__ __align__(16) unsigned short xbuf[2][16 * 392];  // x-gates, padded rows
  __shared__ int tokl[T_ * 16];

  for (int i = tid; i < 2 * 16 * 136; i += 512) ((unsigned short*)hb)[i] = 0;
  for (int i = tid; i < T_ * 16; i += 512) {
    int t = i >> 4, bl = i & 15;
    tokl[i] = tokens[(s * T_ + t) * B_ + bbase + bl] * 768 + dir * 384;
  }

  s8v af[3][4];
  float hbn[4];
  const float* whd = whh + (size_t)dir * (384 * 128);
  const float* bhd = bhh + dir * 384;
  for (int g3 = 0; g3 < 3; ++g3)
    for (int kf = 0; kf < 4; ++kf)
      af[g3][kf] = cvt8(&whd[(size_t)(g3 * 128 + gbase + ln) * 128 + kf * 32 + q * 8]);
  for (int r = 0; r < 4; ++r) hbn[r] = bhd[256 + gbase + q * 4 + r];  // n-gate only
  float h[4] = {0.f, 0.f, 0.f, 0.f};

  // staging geometry: waves 0..5 cover 16 rows x 384 elems (6144 elems) as
  // 12 wave-instrs of 64 lanes x 8 elems (16B). Per-lane constants.
  const bool stager = (w < 6);
  int sr0 = 0, sof0 = 0, sd0 = 0, sr1 = 0, sof1 = 0, sd1 = 0;
  {
    int e0 = w * 1024 + l * 8;
    int e1 = e0 + 512;
    sr0 = e0 / 384; sof0 = e0 - sr0 * 384; sd0 = sr0 * 392 + sof0;
    sr1 = e1 / 384; sof1 = e1 - sr1 * 384; sd1 = sr1 * 392 + sof1;
  }
  int4 ldA, ldB;
#define XLOAD(st)                                                           \
  do {                                                                      \
    int tt_ = (st) > (T_ - 1) ? (T_ - 1) : (st);                            \
    int tg_ = dir ? (T_ - 1 - tt_) : tt_;                                   \
    ldA = *(const int4*)&gtab[(size_t)tokl[tg_ * 16 + sr0] + sof0];         \
    ldB = *(const int4*)&gtab[(size_t)tokl[tg_ * 16 + sr1] + sof1];         \
  } while (0)
#define XWRITE(sl)                                                          \
  do {                                                                      \
    *(int4*)&xbuf[sl][sd0] = ldA;                                           \
    *(int4*)&xbuf[sl][sd1] = ldB;                                           \
  } while (0)

  __syncthreads();                 // tokl + hb zeros visible
  if (stager) {
    XLOAD(0);                      // step-0 gates
    XWRITE(0);                     // (compiler inserts vmcnt wait)
    XLOAD(1);                      // step-1 gates -> regs
  }
  __syncthreads();                 // xbuf slot 0 ready for all waves

  const int xb = ln * 392 + gbase + q * 4;   // per-lane x-read base (constant)
  int p = 0;
  int tprev = 0;
  for (int step = 0; step < T_; ++step) {
    const int t = dir ? (T_ - 1 - step) : step;
    const int sl = step & 1;
    if (stager) {
      XWRITE(sl ^ 1);              // data for step+1 (slot freed by barrier)
      XLOAD(step + 2);             // prefetch step+2 into regs
    }
    if (step > 0 && tid < 256) {   // coalesced iout write of PREVIOUS step
      int row = tid >> 4, kc = tid & 15;
      int4 v = *(const int4*)&hb[p][row * 136 + kc * 8];
      *(int4*)&iout[((size_t)(s * T_ + tprev) * B_ + bbase + row) * 256 +
                    dir * 128 + kc * 8] = v;
    }
    s8v bfr[4];
    for (int kf = 0; kf < 4; ++kf)
      bfr[kf] = *(const s8v*)&hb[p][ln * 136 + kf * 32 + q * 8];
    f32x4 c0 = {0.f, 0.f, 0.f, 0.f}, c1 = c0, c2 = c0;
    for (int kf = 0; kf < 4; ++kf) {
      c0 = mfma16(af[0][kf], bfr[kf], c0);
      c1 = mfma16(af[1][kf], bfr[kf], c1);
      c2 = mfma16(af[2][kf], bfr[kf], c2);
    }
    const ushort4 xr = *(const ushort4*)&xbuf[sl][xb];
    const ushort4 xz = *(const ushort4*)&xbuf[sl][xb + 128];
    const ushort4 xn = *(const ushort4*)&xbuf[sl][xb + 256];
    const unsigned short* xrp = (const unsigned short*)&xr;
    const unsigned short* xzp = (const unsigned short*)&xz;
    const unsigned short* xnp = (const unsigned short*)&xn;
    unsigned short hnb[4];
    for (int r = 0; r < 4; ++r) {
      float rr = fsigm(b2f(xrp[r]) + c0[r]);                 // bhh_r folded
      float zz = fsigm(b2f(xzp[r]) + c1[r]);                 // bhh_z folded
      float nn = ftanh(b2f(xnp[r]) + rr * (c2[r] + hbn[r])); // bhh_n inside r*()
      float hv = zz * (h[r] - nn) + nn;
      h[r] = hv;
      hnb[r] = f2b(hv);
    }
    ushort4 hv4; hv4.x = hnb[0]; hv4.y = hnb[1]; hv4.z = hnb[2]; hv4.w = hnb[3];
    *(ushort4*)&hb[p ^ 1][ln * 136 + g0] = hv4;
    lds_barrier();
    p ^= 1;
    tprev = t;
  }
  // epilogue: write the final step's h tile
  if (tid < 256) {
    int row = tid >> 4, kc = tid & 15;
    int4 v = *(const int4*)&hb[p][row * 136 + kc * 8];
    *(int4*)&iout[((size_t)(s * T_ + tprev) * B_ + bbase + row) * 256 +
                  dir * 128 + kc * 8] = v;
  }
#undef XLOAD
#undef XWRITE
}

// ============================================================================
// K3 (fused attn + xgi): one pass over iout. Grid 256 = (s, b-group of 8).
// Full W_W_intra (128 KB) in LDS; flash-style single iout read; cross-wave
// merge through the freed W region; THEN the inter input-gate GEMM
// (xgi = sv @ WihI^T + biases) fused on the block's 8 sv rows via bf16 MFMA.
// ============================================================================
__global__ __launch_bounds__(512, 1) void k_attn(
    const unsigned short* __restrict__ iout,  // bf16 internal
    const unsigned short* __restrict__ wta,   // bf16 [256][256] n-major
    const float* __restrict__ bint,           // [256] fp32
    const float* __restrict__ proj,           // [256] fp32
    const unsigned short* __restrict__ wib,   // bf16 [768][256] (WihI)
    const float* __restrict__ bihI,           // [768] fp32
    const float* __restrict__ bhhI,           // [768] fp32
    float* __restrict__ xgi)                  // [2][2048][384] fp32
{
  __shared__ __align__(16) unsigned short wlds[256 * 256];  // 128 KB, XOR-swizzled
  __shared__ float lgbuf[8][16];
  __shared__ float lbuf[8][8];
  const int tid = threadIdx.x, bid = blockIdx.x;
  const int s = bid >> 3, b0 = (bid & 7) * 8;
  // stage full W (both halves)
  for (int i = 0; i < 16; ++i) {
    int cid = i * 512 + tid;          // 8192 16B chunks
    int n = cid >> 5, kc = cid & 31;
    *(int4*)&wlds[n * 256 + ((kc ^ (n & 15)) << 3)] =
        *(const int4*)&wta[(size_t)n * 256 + kc * 8];
  }
  const int w = tid >> 6, l = tid & 63, q = l >> 4, ln = l & 15;
  float bbv[16], ppv[16];
  for (int nt = 0; nt < 16; ++nt) {     // per-lane bias/proj for its n-cols
    bbv[nt] = bint[nt * 16 + ln];
    ppv[nt] = proj[nt * 16 + ln];
  }
  __syncthreads();

  float O[8][8];                        // [kf][j] weighted-sum accumulator
  for (int kf = 0; kf < 8; ++kf)
    for (int j = 0; j < 8; ++j) O[kf][j] = 0.f;
  float l_acc = 0.f;

  for (int tile = 0; tile < 4; ++tile) {  // wave w owns t = 8w .. 8w+7
    const int t = (w * 4 + tile) * 2 + (ln >> 3);
    const size_t row = (size_t)((s * T_ + t) * B_ + b0 + (ln & 7));
    s8v af[8];
    for (int kf = 0; kf < 8; ++kf)
      af[kf] = *(const s8v*)&iout[row * 256 + kf * 32 + q * 8];
    float p0 = 0.f, p1 = 0.f, p2 = 0.f, p3 = 0.f;
    for (int nt = 0; nt < 16; ++nt) {
      f32x4 c = {0.f, 0.f, 0.f, 0.f};
      for (int kf = 0; kf < 8; ++kf) {
        s8v bf = *(const s8v*)&wlds[(nt * 16 + ln) * 256 + (((kf * 4 + q) ^ ln) << 3)];
        c = mfma16(af[kf], bf, c);
      }
      p0 += ppv[nt] * ftanh(c[0] + bbv[nt]);
      p1 += ppv[nt] * ftanh(c[1] + bbv[nt]);
      p2 += ppv[nt] * ftanh(c[2] + bbv[nt]);
      p3 += ppv[nt] * ftanh(c[3] + bbv[nt]);
    }
    for (int d = 1; d < 16; d <<= 1) {   // reduce over n-col lanes
      p0 += __shfl_xor(p0, d); p1 += __shfl_xor(p1, d);
      p2 += __shfl_xor(p2, d); p3 += __shfl_xor(p3, d);
    }
    // remap logits (held per D-row q*4+r) to A-row layout via same-wave LDS
    if (ln == 0) {
      lgbuf[w][q * 4 + 0] = p0; lgbuf[w][q * 4 + 1] = p1;
      lgbuf[w][q * 4 + 2] = p2; lgbuf[w][q * 4 + 3] = p3;
    }
    const float lg = lgbuf[w][ln];       // logit for THIS lane's (t,b) row
    const float e = __builtin_amdgcn_exp2f(1.44269504f * lg);
    l_acc += e;
    for (int kf = 0; kf < 8; ++kf)
      for (int j = 0; j < 8; ++j)
        O[kf][j] += e * b2f((unsigned short)af[kf][j]);
  }
  // merge t-pair lanes (ln, ln+8): same b, same dims
  l_acc += __shfl_xor(l_acc, 8);
  for (int kf = 0; kf < 8; ++kf)
    for (int j = 0; j < 8; ++j) O[kf][j] += __shfl_xor(O[kf][j], 8);
  __syncthreads();                       // everyone done reading wlds
  float* obuf = (float*)wlds;            // overlay [0..64K): [8 waves][8 b][256 d]
  unsigned short* svl = (unsigned short*)(((char*)wlds) + 65536);  // [16][264] bf16
  if (ln < 8) {
    const int base = w * 2048 + ln * 256 + q * 8;
    for (int kf = 0; kf < 8; ++kf) {
      float4 v0; v0.x = O[kf][0]; v0.y = O[kf][1]; v0.z = O[kf][2]; v0.w = O[kf][3];
      float4 v1; v1.x = O[kf][4]; v1.y = O[kf][5]; v1.z = O[kf][6]; v1.w = O[kf][7];
      *(float4*)&obuf[base + kf * 32]     = v0;
      *(float4*)&obuf[base + kf * 32 + 4] = v1;
    }
    if (q == 0) lbuf[w][ln] = l_acc;
  }
  // zero pad rows 8..15 of svl (A-operand padding for the M=8 GEMM)
  {
    ushort4 z4; z4.x = 0; z4.y = 0; z4.z = 0; z4.w = 0;
    int rr = 8 + (tid >> 6), cc = (tid & 63) * 4;  // 8 rows x 256 cols, pad ignored
    *(ushort4*)&svl[rr * 264 + cc] = z4;
  }
  __syncthreads();
  // deterministic 8-way reduce + softmax normalize -> sv (bf16, into svl)
  const int idx = tid * 4;               // 2048 outputs / 512 threads
  const int bb_ = idx >> 8;
  float4 acc; acc.x = 0.f; acc.y = 0.f; acc.z = 0.f; acc.w = 0.f;
  float lsum = 0.f;
  for (int w8 = 0; w8 < 8; ++w8) {
    const float4 v = *(const float4*)&obuf[w8 * 2048 + idx];
    acc.x += v.x; acc.y += v.y; acc.z += v.z; acc.w += v.w;
    lsum += lbuf[w8][bb_];
  }
  const float inv = __builtin_amdgcn_rcpf(lsum);
  ushort4 u;
  u.x = f2b_rne(acc.x * inv); u.y = f2b_rne(acc.y * inv);
  u.z = f2b_rne(acc.z * inv); u.w = f2b_rne(acc.w * inv);
  *(ushort4*)&svl[bb_ * 264 + (idx & 255)] = u;
  __syncthreads();
  // ---- fused xgi GEMM: out[m=0..7][c=0..767] = sv . WihI[c] + bias ----
  s8v afx[8];
  for (int kf = 0; kf < 8; ++kf)
    afx[kf] = *(const s8v*)&svl[ln * 264 + kf * 32 + q * 8];
  for (int nt = 0; nt < 6; ++nt) {
    const int c = w * 96 + nt * 16 + ln;  // col 0..767
    const int dirI = (c >= 384) ? 1 : 0;
    const int g = c - dirI * 384;
    const float biasx = bihI[c] + (g < 256 ? bhhI[c] : 0.f);  // fold r,z
    f32x4 cacc = {0.f, 0.f, 0.f, 0.f};
    for (int kf = 0; kf < 8; ++kf) {
      s8v bfx = *(const s8v*)&wib[(size_t)c * 256 + kf * 32 + q * 8];
      cacc = mfma16(afx[kf], bfx, cacc);
    }
    if (q < 2) {                          // rows 0..7 are real sv rows
      for (int r = 0; r < 4; ++r) {
        const int m = q * 4 + r;
        xgi[((size_t)dirI * 2048 + s * B_ + b0 + m) * 384 + g] = cacc[r] + biasx;
      }
    }
  }
}

// ============================================================================
// K5: inter biGRU. Grid 8 = (dir, b-quad of 16). Depth-3 pipelined gate loads.
// ============================================================================
__global__ __launch_bounds__(512) void k_inter(
    const float* __restrict__ xgi,   // r,z biases folded
    const float* __restrict__ whh,   // [2][384][128] fp32
    const float* __restrict__ bhh,   // [2][384] fp32 (n-gate used)
    float* __restrict__ io2)         // [S*B][256] fp32
{
  const int bid = blockIdx.x;
  const int dir = bid >> 2, bq = bid & 3, bbase = bq * 16;
  const int tid = threadIdx.x;
  const int w = tid >> 6, l = tid & 63, q = l >> 4, ln = l & 15;
  const int gbase = w * 16, g0 = gbase + q * 4;
  __shared__ __align__(16) unsigned short hb[2][16 * 136];
  for (int i = tid; i < 2 * 16 * 136; i += 512) ((unsigned short*)hb)[i] = 0;
  s8v af[3][4];
  float hbn[4];
  const float* whd = whh + (size_t)dir * (384 * 128);
  const float* bhd = bhh + dir * 384;
  for (int g3 = 0; g3 < 3; ++g3) {
    const int R = g3 * 128 + gbase;
    for (int kf = 0; kf < 4; ++kf)
      af[g3][kf] = cvt8(&whd[(size_t)(R + ln) * 128 + kf * 32 + q * 8]);
  }
  for (int r = 0; r < 4; ++r) hbn[r] = bhd[256 + gbase + q * 4 + r];
  float h[4] = {0.f, 0.f, 0.f, 0.f};
  const int b = bbase + ln;
  __syncthreads();

  float4 Vr[4], Vz[4], Vn[4];
#define GLOAD_S(slot, st)                                                   \
  do {                                                                      \
    int tt_ = (st) > (S_ - 1) ? (S_ - 1) : (st);                            \
    int sg_ = dir ? (S_ - 1 - tt_) : tt_;                                   \
    const float* xp_ = xgi + ((size_t)dir * 2048 + sg_ * 64 + b) * 384 + g0;\
    Vr[slot] = *(const float4*)&xp_[0];                                     \
    Vz[slot] = *(const float4*)&xp_[128];                                   \
    Vn[slot] = *(const float4*)&xp_[256];                                   \
  } while (0)

  GLOAD_S(0, 0);
  GLOAD_S(1, 1);
  GLOAD_S(2, 2);

  int p = 0;
  for (int it = 0; it < S_ / 4; ++it) {
#pragma unroll
    for (int j = 0; j < 4; ++j) {
      const int step = it * 4 + j;
      const int sI = dir ? (S_ - 1 - step) : step;
      GLOAD_S((j + 3) & 3, step + 3);

      s8v bfr[4];
      for (int kf = 0; kf < 4; ++kf)
        bfr[kf] = *(const s8v*)&hb[p][ln * 136 + kf * 32 + q * 8];
      f32x4 c0 = {0.f, 0.f, 0.f, 0.f}, c1 = c0, c2 = c0;
      for (int kf = 0; kf < 4; ++kf) {
        c0 = mfma16(af[0][kf], bfr[kf], c0);
        c1 = mfma16(af[1][kf], bfr[kf], c1);
        c2 = mfma16(af[2][kf], bfr[kf], c2);
      }
      const float irv[4] = {Vr[j].x, Vr[j].y, Vr[j].z, Vr[j].w};
      const float izv[4] = {Vz[j].x, Vz[j].y, Vz[j].z, Vz[j].w};
      const float inv[4] = {Vn[j].x, Vn[j].y, Vn[j].z, Vn[j].w};
      unsigned short hnb[4];
      for (int r = 0; r < 4; ++r) {
        float rr = fsigm(irv[r] + c0[r]);
        float zz = fsigm(izv[r] + c1[r]);
        float nn = ftanh(inv[r] + rr * (c2[r] + hbn[r]));
        float hv = zz * (h[r] - nn) + nn;
        h[r] = hv;
        hnb[r] = f2b(hv);
      }
      ushort4 hv4; hv4.x = hnb[0]; hv4.y = hnb[1]; hv4.z = hnb[2]; hv4.w = hnb[3];
      *(ushort4*)&hb[p ^ 1][ln * 136 + g0] = hv4;
      float4 of4; of4.x = h[0]; of4.y = h[1]; of4.z = h[2]; of4.w = h[3];
      *(float4*)&io2[((size_t)(sI * 64 + b)) * 256 + dir * 128 + g0] = of4;
      lds_barrier();
      p ^= 1;
    }
  }
#undef GLOAD_S
}

// ============================================================================
// K6: a2[s*64+b] = proj_inter . tanh(io2 @ W_W_inter + b_inter)  (no softmax)
// ============================================================================
__global__ __launch_bounds__(256) void k_attn_i(
    const float* __restrict__ io2,
    const float* __restrict__ wwI,   // [256][256] fp32 h-major
    const float* __restrict__ bI,
    const float* __restrict__ projI,
    float* __restrict__ a2)          // [2048]
{
  const int bid = blockIdx.x, tid = threadIdx.x;
  const int r0 = bid * 8;
  __shared__ float iol[8 * 256];
  __shared__ float red[4 * 8];
  for (int i = 0; i < 8; ++i) iol[i * 256 + tid] = io2[(size_t)(r0 + i) * 256 + tid];
  __syncthreads();
  float acc[8];
  for (int i = 0; i < 8; ++i) acc[i] = 0.f;
  for (int hh = 0; hh < 256; ++hh) {
    const float wv = wwI[hh * 256 + tid];
    for (int i = 0; i < 8; ++i) acc[i] += wv * iol[i * 256 + hh];
  }
  const float bb = bI[tid], pp = projI[tid];
  float p[8];
  for (int i = 0; i < 8; ++i) p[i] = pp * ftanh(acc[i] + bb);
  for (int d = 1; d < 64; d <<= 1)
    for (int i = 0; i < 8; ++i) p[i] += __shfl_xor(p[i], d);
  const int w = tid >> 6, l = tid & 63;
  if (l == 0)
    for (int i = 0; i < 8; ++i) red[w * 8 + i] = p[i];
  __syncthreads();
  if (tid < 8) a2[r0 + tid] = red[tid] + red[8 + tid] + red[16 + tid] + red[24 + tid];
}

// ============================================================================
// K7: doc_vec = sum_s a2 * io2 ; out = doc @ W_final^T + b_final  (fp32 out)
// ============================================================================
__global__ __launch_bounds__(256) void k_final(
    const float* __restrict__ a2,
    const float* __restrict__ io2,
    const float* __restrict__ wf,    // [5][256] fp32
    const float* __restrict__ bfi,   // [5] fp32
    float* __restrict__ out)         // [64][5] fp32
{
  const int b = blockIdx.x, tid = threadIdx.x;
  __shared__ float av[S_];
  __shared__ float dv[256];
  __shared__ float red[4];
  if (tid < S_) av[tid] = a2[tid * 64 + b];
  __syncthreads();
  float acc = 0.f;
  for (int s = 0; s < S_; ++s) acc += av[s] * io2[((size_t)(s * 64 + b)) * 256 + tid];
  dv[tid] = acc;
  __syncthreads();
  for (int c = 0; c < C_; ++c) {
    float pv = wf[c * 256 + tid] * dv[tid];
    for (int d = 1; d < 64; d <<= 1) pv += __shfl_xor(pv, d);
    const int w = tid >> 6, l = tid & 63;
    if (l == 0) red[w] = pv;
    __syncthreads();
    if (tid == 0)
      out[b * C_ + c] = red[0] + red[1] + red[2] + red[3] + bfi[c];
    __syncthreads();
  }
}

// ============================================================================
extern "C" void kernel_launch(void* const* d_in, const int* in_sizes, int n_in,
                              void* d_out, int out_size, void* d_ws, size_t ws_size,
                              hipStream_t stream) {
  (void)in_sizes; (void)n_in; (void)out_size; (void)ws_size;
  const int*   tokens = (const int*)d_in[0];
  const float* emb    = (const float*)d_in[1];
  const float* wih_a  = (const float*)d_in[2];
  const float* whh_a  = (const float*)d_in[3];
  const float* bih_a  = (const float*)d_in[4];
  const float* bhh_a  = (const float*)d_in[5];
  const float* ww_a   = (const float*)d_in[6];
  const float* b_a    = (const float*)d_in[7];
  const float* proj_a = (const float*)d_in[8];
  const float* wih_i  = (const float*)d_in[9];
  const float* whh_i  = (const float*)d_in[10];
  const float* bih_i  = (const float*)d_in[11];
  const float* bhh_i  = (const float*)d_in[12];
  const float* ww_i   = (const float*)d_in[13];
  const float* b_i    = (const float*)d_in[14];
  const float* proj_i = (const float*)d_in[15];
  const float* w_fin  = (const float*)d_in[16];
  const float* b_fin  = (const float*)d_in[17];

  char* ws = (char*)d_ws;
  unsigned short* gtab = (unsigned short*)(ws + 0);          // 49,152,000 B
  unsigned short* wta  = (unsigned short*)(ws + 49152000);   //    131,072 B
  unsigned short* iout = (unsigned short*)(ws + 49283072);   // 67,108,864 B
  unsigned short* wib  = (unsigned short*)(ws + 116391936);  //    393,216 B
  float* xgi = (float*)(ws + 119537664);                     //  6,291,456 B
  float* io2 = (float*)(ws + 125829120);                     //  2,097,152 B
  float* a2  = (float*)(ws + 127926272);                     //      8,192 B

  k_gtab<<<508, 256, 0, stream>>>(emb, wih_a, bih_a, bhh_a, ww_a, wih_i,
                                  gtab, wta, wib);
  k_intra<<<256, 512, 0, stream>>>(tokens, gtab, whh_a, bhh_a, iout);
  k_attn<<<256, 512, 0, stream>>>(iout, wta, b_a, proj_a, wib, bih_i, bhh_i, xgi);
  k_inter<<<8, 512, 0, stream>>>(xgi, whh_i, bhh_i, io2);
  k_attn_i<<<256, 256, 0, stream>>>(io2, ww_i, b_i, proj_i, a2);
  k_final<<<64, 256, 0, stream>>>(a2, io2, w_fin, b_fin, (float*)d_out);
}

// Round 8
// 294.318 us; speedup vs baseline: 1.1500x; 1.0214x over previous
//
#include <hip/hip_runtime.h>

// Problem dims
#define S_ 32
#define T_ 64
#define B_ 64
#define V_ 32000
#define E_ 128
#define H_ 128
#define G_ 128
#define C_ 5

typedef short s8v __attribute__((ext_vector_type(8)));   // 8 bf16 payload
typedef __bf16 b8v __attribute__((ext_vector_type(8)));
typedef float f32x4 __attribute__((ext_vector_type(4)));

// --- MFMA wrapper: tolerate either builtin operand signature (short8 or bf16x8)
template <typename V>
__device__ inline auto mfma_sel(V a, V b, f32x4 c, int)
    -> decltype(__builtin_amdgcn_mfma_f32_16x16x32_bf16(a, b, c, 0, 0, 0)) {
  return __builtin_amdgcn_mfma_f32_16x16x32_bf16(a, b, c, 0, 0, 0);
}
template <typename V>
__device__ inline f32x4 mfma_sel(V a, V b, f32x4 c, long) {
  return __builtin_amdgcn_mfma_f32_16x16x32_bf16(
      __builtin_bit_cast(b8v, a), __builtin_bit_cast(b8v, b), c, 0, 0, 0);
}
__device__ inline f32x4 mfma16(s8v a, s8v b, f32x4 c) { return mfma_sel(a, b, c, 0); }

__device__ inline float b2f(unsigned short u) {
  union { unsigned int i; float f; } v; v.i = ((unsigned int)u) << 16; return v.f;
}
// round-to-nearest (ties away) — 2 instr; RNE tie diff is <=1ulp, irrelevant at 2% tol
__device__ inline unsigned short f2b(float f) {
  union { float f; unsigned int i; } v; v.f = f;
  return (unsigned short)((v.i + 0x8000u) >> 16);
}
// full-RNE for the precomputed tables (cheap there, done once per element)
__device__ inline unsigned short f2b_rne(float f) {
  union { float f; unsigned int i; } v; v.f = f;
  unsigned int r = (v.i + 0x7fffu + ((v.i >> 16) & 1u)) >> 16;
  return (unsigned short)r;
}
__device__ inline s8v cvt8(const float* p) {
  const float4 a = *(const float4*)p;
  const float4 b = *(const float4*)(p + 4);
  s8v r;
  r[0] = (short)f2b_rne(a.x); r[1] = (short)f2b_rne(a.y);
  r[2] = (short)f2b_rne(a.z); r[3] = (short)f2b_rne(a.w);
  r[4] = (short)f2b_rne(b.x); r[5] = (short)f2b_rne(b.y);
  r[6] = (short)f2b_rne(b.z); r[7] = (short)f2b_rne(b.w);
  return r;
}
// division-free activations: raw v_rcp_f32 + v_exp_f32 (1 instr each).
__device__ inline float fsigm(float x) {
  return __builtin_amdgcn_rcpf(1.f + __builtin_amdgcn_exp2f(-1.44269504f * x));
}
__device__ inline float ftanh(float x) {
  return 1.f - 2.f * __builtin_amdgcn_rcpf(1.f + __builtin_amdgcn_exp2f(2.88539008f * x));
}

// LDS-only barrier: waits LDS ops, does NOT drain vmcnt — global loads issued
// before this stay in flight across it (cross-wave data here is LDS-only).
__device__ inline void lds_barrier() {
  asm volatile("s_waitcnt lgkmcnt(0)\n\ts_barrier" ::: "memory");
}

// ============================================================================
// K1: gtab[v][c] = sum_e emb[v][e]*Wih_intra[c][e] + bih[c] (+bhh[c] folded for
// r,z gates). MFMA GEMM: 500 blocks own a 64-row emb tile and iterate ALL 6
// N-chunks. NEW: results accumulate in a row-padded LDS tile (776-elem rows,
// bank-spread u16 writes) and go to HBM as coalesced int4 stores — the old
// path emitted 49 MB via scattered 2-BYTE stores (write-transaction-bound
// suspect for the invisible #2 kernel). Blocks 500..503: transpose W_W_intra
// (reuses the result buffer). Blocks 504..507: convert Wih_inter -> bf16.
// ============================================================================
__global__ __launch_bounds__(256) void k_gtab(
    const float* __restrict__ emb,
    const float* __restrict__ wih,   // [768][128] fp32
    const float* __restrict__ bih,   // [768] fp32
    const float* __restrict__ bhh,   // [768] fp32 (r,z folded; n NOT)
    const float* __restrict__ wwi,   // [256][256] fp32 (h-major)
    const float* __restrict__ wihI,  // [768][256] fp32 (inter input weights)
    unsigned short* __restrict__ gtab,   // [V][768] bf16
    unsigned short* __restrict__ wta,    // [256][256] bf16 (n-major)
    unsigned short* __restrict__ wib)    // [768][256] bf16
{
  __shared__ __align__(16) unsigned short res[64 * 776];   // 99.3 KB result tile
  __shared__ __align__(16) unsigned short alds[64 * 136];  // 17.4 KB emb tile
  const int bid = blockIdx.x, tid = threadIdx.x;
  if (bid >= 504) {  // wihI fp32 -> bf16, 4 blocks
    const int cb = bid - 504;
    for (int i = 0; i < 48; ++i) {
      int e4 = cb * 12288 + i * 256 + tid;  // float4 index
      float4 v = *(const float4*)&wihI[(size_t)e4 * 4];
      ushort4 u;
      u.x = f2b_rne(v.x); u.y = f2b_rne(v.y); u.z = f2b_rne(v.z); u.w = f2b_rne(v.w);
      *(ushort4*)&wib[(size_t)e4 * 4] = u;
    }
    return;
  }
  if (bid >= 500) {  // LDS-tiled transpose, 4 blocks x 64 n-rows (uses res buf)
    const int n0 = (bid - 500) * 64;
    for (int i = 0; i < 64; ++i) {
      int cid = i * 256 + tid;
      int k = cid >> 6, nl = cid & 63;
      res[nl * 264 + k] = f2b_rne(wwi[k * 256 + n0 + nl]);   // coalesced read
    }
    __syncthreads();
    for (int i = 0; i < 8; ++i) {
      int cid = i * 256 + tid;
      int nl = cid >> 5, k8 = cid & 31;
      *(int4*)&wta[(size_t)(n0 + nl) * 256 + k8 * 8] =
          *(const int4*)&res[nl * 264 + k8 * 8];             // coalesced write
    }
    return;
  }
  const int vbase = bid * 64;
  for (int i = 0; i < 8; ++i) {
    int cid = i * 256 + tid;           // 2048 chunks of 4 floats
    int row = cid >> 5, kc = cid & 31;
    float4 v = *(const float4*)&emb[(size_t)(vbase + row) * 128 + kc * 4];
    ushort4 u;
    u.x = f2b_rne(v.x); u.y = f2b_rne(v.y); u.z = f2b_rne(v.z); u.w = f2b_rne(v.w);
    *(ushort4*)&alds[row * 136 + kc * 4] = u;
  }
  __syncthreads();
  const int w = tid >> 6, l = tid & 63, q = l >> 4, ln = l & 15;
  // hoist all A fragments (16 s8v = 64 VGPR) — reused across 6 N-chunks
  s8v af[4][4];
  for (int mt = 0; mt < 4; ++mt)
    for (int kf = 0; kf < 4; ++kf)
      af[mt][kf] = *(const s8v*)&alds[(mt * 16 + ln) * 136 + kf * 32 + q * 8];
  for (int nchunk = 0; nchunk < 6; ++nchunk) {
    const int nbase = nchunk * 128;
    s8v bf[2][4];
    float bias[2];
    for (int nt = 0; nt < 2; ++nt) {
      int c = nbase + (w * 2 + nt) * 16 + ln;
      int g = (c < 384) ? c : (c - 384);       // gate index within direction
      bias[nt] = bih[c] + (g < 256 ? bhh[c] : 0.f);  // fold r,z recurrent bias
      for (int kf = 0; kf < 4; ++kf)
        bf[nt][kf] = cvt8(&wih[(size_t)c * 128 + kf * 32 + q * 8]);
    }
    for (int mt = 0; mt < 4; ++mt) {
      for (int nt = 0; nt < 2; ++nt) {
        f32x4 acc = {0.f, 0.f, 0.f, 0.f};
        for (int kf = 0; kf < 4; ++kf) acc = mfma16(af[mt][kf], bf[nt][kf], acc);
        const int col = nbase + (w * 2 + nt) * 16 + ln;
        for (int r = 0; r < 4; ++r) {
          const int row = mt * 16 + q * 4 + r;
          res[row * 776 + col] = f2b_rne(acc[r] + bias[nt]);  // LDS u16, spread
        }
      }
    }
  }
  __syncthreads();
  // coalesced writeout: 64 rows x 96 int4 = 6144 chunks, 24 per thread
  for (int i = 0; i < 24; ++i) {
    int cid = i * 256 + tid;
    int row = cid / 96, kc = cid - row * 96;
    *(int4*)&gtab[(size_t)(vbase + row) * 768 + kc * 8] =
        *(const int4*)&res[row * 776 + kc * 8];
  }
}

// ============================================================================
// K2: intra biGRU. Grid 256 = (s, dir, b-quad of 16), 8 waves (R3 structure).
// Wide staged gather (waves 0..5, reg->LDS dbuf) + coalesced iout writeout.
// Issue-bandwidth-bound per analysis (VALUBusy 43% = ~1100cy/step issue on 2
// waves/SIMD incl. 24 quarter-rate trans/lane); left untouched this round.
// ============================================================================
__global__ __launch_bounds__(512) void k_intra(
    const int* __restrict__ tokens,
    const unsigned short* __restrict__ gtab,  // bf16, r/z biases folded
    const float* __restrict__ whh,            // [2][384][128] fp32
    const float* __restrict__ bhh,            // [2][384] fp32 (n-gate used)
    unsigned short* __restrict__ iout)        // [S*T*B][256] bf16 internal
{
  const int bid = blockIdx.x;
  const int s = bid >> 3, dir = (bid >> 2) & 1, bq = bid & 3;
  const int bbase = bq * 16;
  const int tid = threadIdx.x;
  const int w = tid >> 6, l = tid & 63, q = l >> 4, ln = l & 15;
  const int gbase = w * 16, g0 = gbase + q * 4;

  __shared__ __align__(16) unsigned short hb[2][16 * 136];    // h state (dbuf)
  __shared__ __align__(16) unsigned short xbuf[2][16 * 392];  // x-gates, padded rows
  __shared__ int tokl[T_ * 16];

  for (int i = tid; i < 2 * 16 * 136; i += 512) ((unsigned short*)hb)[i] = 0;
  for (int i = tid; i < T_ * 16; i += 512) {
    int t = i >> 4, bl = i & 15;
    tokl[i] = tokens[(s * T_ + t) * B_ + bbase + bl] * 768 + dir * 384;
  }

  s8v af[3][4];
  float hbn[4];
  const float* whd = whh + (size_t)dir * (384 * 128);
  const float* bhd = bhh + dir * 384;
  for (int g3 = 0; g3 < 3; ++g3)
    for (int kf = 0; kf < 4; ++kf)
      af[g3][kf] = cvt8(&whd[(size_t)(g3 * 128 + gbase + ln) * 128 + kf * 32 + q * 8]);
  for (int r = 0; r < 4; ++r) hbn[r] = bhd[256 + gbase + q * 4 + r];  // n-gate only
  float h[4] = {0.f, 0.f, 0.f, 0.f};

  // staging geometry: waves 0..5 cover 16 rows x 384 elems (6144 elems) as
  // 12 wave-instrs of 64 lanes x 8 elems (16B). Per-lane constants.
  const bool stager = (w < 6);
  int sr0 = 0, sof0 = 0, sd0 = 0, sr1 = 0, sof1 = 0, sd1 = 0;
  {
    int e0 = w * 1024 + l * 8;
    int e1 = e0 + 512;
    sr0 = e0 / 384; sof0 = e0 - sr0 * 384; sd0 = sr0 * 392 + sof0;
    sr1 = e1 / 384; sof1 = e1 - sr1 * 384; sd1 = sr1 * 392 + sof1;
  }
  int4 ldA, ldB;
#define XLOAD(st)                                                           \
  do {                                                                      \
    int tt_ = (st) > (T_ - 1) ? (T_ - 1) : (st);                            \
    int tg_ = dir ? (T_ - 1 - tt_) : tt_;                                   \
    ldA = *(const int4*)&gtab[(size_t)tokl[tg_ * 16 + sr0] + sof0];         \
    ldB = *(const int4*)&gtab[(size_t)tokl[tg_ * 16 + sr1] + sof1];         \
  } while (0)
#define XWRITE(sl)                                                          \
  do {                                                                      \
    *(int4*)&xbuf[sl][sd0] = ldA;                                           \
    *(int4*)&xbuf[sl][sd1] = ldB;                                           \
  } while (0)

  __syncthreads();                 // tokl + hb zeros visible
  if (stager) {
    XLOAD(0);                      // step-0 gates
    XWRITE(0);                     // (compiler inserts vmcnt wait)
    XLOAD(1);                      // step-1 gates -> regs
  }
  __syncthreads();                 // xbuf slot 0 ready for all waves

  const int xb = ln * 392 + gbase + q * 4;   // per-lane x-read base (constant)
  int p = 0;
  int tprev = 0;
  for (int step = 0; step < T_; ++step) {
    const int t = dir ? (T_ - 1 - step) : step;
    const int sl = step & 1;
    if (stager) {
      XWRITE(sl ^ 1);              // data for step+1 (slot freed by barrier)
      XLOAD(step + 2);             // prefetch step+2 into regs
    }
    if (step > 0 && tid < 256) {   // coalesced iout write of PREVIOUS step
      int row = tid >> 4, kc = tid & 15;
      int4 v = *(const int4*)&hb[p][row * 136 + kc * 8];
      *(int4*)&iout[((size_t)(s * T_ + tprev) * B_ + bbase + row) * 256 +
                    dir * 128 + kc * 8] = v;
    }
    s8v bfr[4];
    for (int kf = 0; kf < 4; ++kf)
      bfr[kf] = *(const s8v*)&hb[p][ln * 136 + kf * 32 + q * 8];
    f32x4 c0 = {0.f, 0.f, 0.f, 0.f}, c1 = c0, c2 = c0;
    for (int kf = 0; kf < 4; ++kf) {
      c0 = mfma16(af[0][kf], bfr[kf], c0);
      c1 = mfma16(af[1][kf], bfr[kf], c1);
      c2 = mfma16(af[2][kf], bfr[kf], c2);
    }
    const ushort4 xr = *(const ushort4*)&xbuf[sl][xb];
    const ushort4 xz = *(const ushort4*)&xbuf[sl][xb + 128];
    const ushort4 xn = *(const ushort4*)&xbuf[sl][xb + 256];
    const unsigned short* xrp = (const unsigned short*)&xr;
    const unsigned short* xzp = (const unsigned short*)&xz;
    const unsigned short* xnp = (const unsigned short*)&xn;
    unsigned short hnb[4];
    for (int r = 0; r < 4; ++r) {
      float rr = fsigm(b2f(xrp[r]) + c0[r]);                 // bhh_r folded
      float zz = fsigm(b2f(xzp[r]) + c1[r]);                 // bhh_z folded
      float nn = ftanh(b2f(xnp[r]) + rr * (c2[r] + hbn[r])); // bhh_n inside r*()
      float hv = zz * (h[r] - nn) + nn;
      h[r] = hv;
      hnb[r] = f2b(hv);
    }
    ushort4 hv4; hv4.x = hnb[0]; hv4.y = hnb[1]; hv4.z = hnb[2]; hv4.w = hnb[3];
    *(ushort4*)&hb[p ^ 1][ln * 136 + g0] = hv4;
    lds_barrier();
    p ^= 1;
    tprev = t;
  }
  // epilogue: write the final step's h tile
  if (tid < 256) {
    int row = tid >> 4, kc = tid & 15;
    int4 v = *(const int4*)&hb[p][row * 136 + kc * 8];
    *(int4*)&iout[((size_t)(s * T_ + tprev) * B_ + bbase + row) * 256 +
                  dir * 128 + kc * 8] = v;
  }
#undef XLOAD
#undef XWRITE
}

// ============================================================================
// K3 (fused attn + xgi): one pass over iout. Grid 256 = (s, b-group of 8).
// Full W_W_intra (128 KB) in LDS; flash-style single iout read; cross-wave
// merge through the freed W region; THEN the inter input-gate GEMM
// (xgi = sv @ WihI^T + biases) fused on the block's 8 sv rows via bf16 MFMA.
// ============================================================================
__global__ __launch_bounds__(512, 1) void k_attn(
    const unsigned short* __restrict__ iout,  // bf16 internal
    const unsigned short* __restrict__ wta,   // bf16 [256][256] n-major
    const float* __restrict__ bint,           // [256] fp32
    const float* __restrict__ proj,           // [256] fp32
    const unsigned short* __restrict__ wib,   // bf16 [768][256] (WihI)
    const float* __restrict__ bihI,           // [768] fp32
    const float* __restrict__ bhhI,           // [768] fp32
    float* __restrict__ xgi)                  // [2][2048][384] fp32
{
  __shared__ __align__(16) unsigned short wlds[256 * 256];  // 128 KB, XOR-swizzled
  __shared__ float lgbuf[8][16];
  __shared__ float lbuf[8][8];
  const int tid = threadIdx.x, bid = blockIdx.x;
  const int s = bid >> 3, b0 = (bid & 7) * 8;
  // stage full W (both halves)
  for (int i = 0; i < 16; ++i) {
    int cid = i * 512 + tid;          // 8192 16B chunks
    int n = cid >> 5, kc = cid & 31;
    *(int4*)&wlds[n * 256 + ((kc ^ (n & 15)) << 3)] =
        *(const int4*)&wta[(size_t)n * 256 + kc * 8];
  }
  const int w = tid >> 6, l = tid & 63, q = l >> 4, ln = l & 15;
  float bbv[16], ppv[16];
  for (int nt = 0; nt < 16; ++nt) {     // per-lane bias/proj for its n-cols
    bbv[nt] = bint[nt * 16 + ln];
    ppv[nt] = proj[nt * 16 + ln];
  }
  __syncthreads();

  float O[8][8];                        // [kf][j] weighted-sum accumulator
  for (int kf = 0; kf < 8; ++kf)
    for (int j = 0; j < 8; ++j) O[kf][j] = 0.f;
  float l_acc = 0.f;

  for (int tile = 0; tile < 4; ++tile) {  // wave w owns t = 8w .. 8w+7
    const int t = (w * 4 + tile) * 2 + (ln >> 3);
    const size_t row = (size_t)((s * T_ + t) * B_ + b0 + (ln & 7));
    s8v af[8];
    for (int kf = 0; kf < 8; ++kf)
      af[kf] = *(const s8v*)&iout[row * 256 + kf * 32 + q * 8];
    float p0 = 0.f, p1 = 0.f, p2 = 0.f, p3 = 0.f;
    for (int nt = 0; nt < 16; ++nt) {
      f32x4 c = {0.f, 0.f, 0.f, 0.f};
      for (int kf = 0; kf < 8; ++kf) {
        s8v bf = *(const s8v*)&wlds[(nt * 16 + ln) * 256 + (((kf * 4 + q) ^ ln) << 3)];
        c = mfma16(af[kf], bf, c);
      }
      p0 += ppv[nt] * ftanh(c[0] + bbv[nt]);
      p1 += ppv[nt] * ftanh(c[1] + bbv[nt]);
      p2 += ppv[nt] * ftanh(c[2] + bbv[nt]);
      p3 += ppv[nt] * ftanh(c[3] + bbv[nt]);
    }
    for (int d = 1; d < 16; d <<= 1) {   // reduce over n-col lanes
      p0 += __shfl_xor(p0, d); p1 += __shfl_xor(p1, d);
      p2 += __shfl_xor(p2, d); p3 += __shfl_xor(p3, d);
    }
    // remap logits (held per D-row q*4+r) to A-row layout via same-wave LDS
    if (ln == 0) {
      lgbuf[w][q * 4 + 0] = p0; lgbuf[w][q * 4 + 1] = p1;
      lgbuf[w][q * 4 + 2] = p2; lgbuf[w][q * 4 + 3] = p3;
    }
    const float lg = lgbuf[w][ln];       // logit for THIS lane's (t,b) row
    const float e = __builtin_amdgcn_exp2f(1.44269504f * lg);
    l_acc += e;
    for (int kf = 0; kf < 8; ++kf)
      for (int j = 0; j < 8; ++j)
        O[kf][j] += e * b2f((unsigned short)af[kf][j]);
  }
  // merge t-pair lanes (ln, ln+8): same b, same dims
  l_acc += __shfl_xor(l_acc, 8);
  for (int kf = 0; kf < 8; ++kf)
    for (int j = 0; j < 8; ++j) O[kf][j] += __shfl_xor(O[kf][j], 8);
  __syncthreads();                       // everyone done reading wlds
  float* obuf = (float*)wlds;            // overlay [0..64K): [8 waves][8 b][256 d]
  unsigned short* svl = (unsigned short*)(((char*)wlds) + 65536);  // [16][264] bf16
  if (ln < 8) {
    const int base = w * 2048 + ln * 256 + q * 8;
    for (int kf = 0; kf < 8; ++kf) {
      float4 v0; v0.x = O[kf][0]; v0.y = O[kf][1]; v0.z = O[kf][2]; v0.w = O[kf][3];
      float4 v1; v1.x = O[kf][4]; v1.y = O[kf][5]; v1.z = O[kf][6]; v1.w = O[kf][7];
      *(float4*)&obuf[base + kf * 32]     = v0;
      *(float4*)&obuf[base + kf * 32 + 4] = v1;
    }
    if (q == 0) lbuf[w][ln] = l_acc;
  }
  // zero pad rows 8..15 of svl (A-operand padding for the M=8 GEMM)
  {
    ushort4 z4; z4.x = 0; z4.y = 0; z4.z = 0; z4.w = 0;
    int rr = 8 + (tid >> 6), cc = (tid & 63) * 4;  // 8 rows x 256 cols, pad ignored
    *(ushort4*)&svl[rr * 264 + cc] = z4;
  }
  __syncthreads();
  // deterministic 8-way reduce + softmax normalize -> sv (bf16, into svl)
  const int idx = tid * 4;               // 2048 outputs / 512 threads
  const int bb_ = idx >> 8;
  float4 acc; acc.x = 0.f; acc.y = 0.f; acc.z = 0.f; acc.w = 0.f;
  float lsum = 0.f;
  for (int w8 = 0; w8 < 8; ++w8) {
    const float4 v = *(const float4*)&obuf[w8 * 2048 + idx];
    acc.x += v.x; acc.y += v.y; acc.z += v.z; acc.w += v.w;
    lsum += lbuf[w8][bb_];
  }
  const float inv = __builtin_amdgcn_rcpf(lsum);
  ushort4 u;
  u.x = f2b_rne(acc.x * inv); u.y = f2b_rne(acc.y * inv);
  u.z = f2b_rne(acc.z * inv); u.w = f2b_rne(acc.w * inv);
  *(ushort4*)&svl[bb_ * 264 + (idx & 255)] = u;
  __syncthreads();
  // ---- fused xgi GEMM: out[m=0..7][c=0..767] = sv . WihI[c] + bias ----
  s8v afx[8];
  for (int kf = 0; kf < 8; ++kf)
    afx[kf] = *(const s8v*)&svl[ln * 264 + kf * 32 + q * 8];
  for (int nt = 0; nt < 6; ++nt) {
    const int c = w * 96 + nt * 16 + ln;  // col 0..767
    const int dirI = (c >= 384) ? 1 : 0;
    const int g = c - dirI * 384;
    const float biasx = bihI[c] + (g < 256 ? bhhI[c] : 0.f);  // fold r,z
    f32x4 cacc = {0.f, 0.f, 0.f, 0.f};
    for (int kf = 0; kf < 8; ++kf) {
      s8v bfx = *(const s8v*)&wib[(size_t)c * 256 + kf * 32 + q * 8];
      cacc = mfma16(afx[kf], bfx, cacc);
    }
    if (q < 2) {                          // rows 0..7 are real sv rows
      for (int r = 0; r < 4; ++r) {
        const int m = q * 4 + r;
        xgi[((size_t)dirI * 2048 + s * B_ + b0 + m) * 384 + g] = cacc[r] + biasx;
      }
    }
  }
}

// ============================================================================
// K5: inter biGRU. Grid 8 = (dir, b-quad of 16). Depth-3 pipelined gate loads.
// ============================================================================
__global__ __launch_bounds__(512) void k_inter(
    const float* __restrict__ xgi,   // r,z biases folded
    const float* __restrict__ whh,   // [2][384][128] fp32
    const float* __restrict__ bhh,   // [2][384] fp32 (n-gate used)
    float* __restrict__ io2)         // [S*B][256] fp32
{
  const int bid = blockIdx.x;
  const int dir = bid >> 2, bq = bid & 3, bbase = bq * 16;
  const int tid = threadIdx.x;
  const int w = tid >> 6, l = tid & 63, q = l >> 4, ln = l & 15;
  const int gbase = w * 16, g0 = gbase + q * 4;
  __shared__ __align__(16) unsigned short hb[2][16 * 136];
  for (int i = tid; i < 2 * 16 * 136; i += 512) ((unsigned short*)hb)[i] = 0;
  s8v af[3][4];
  float hbn[4];
  const float* whd = whh + (size_t)dir * (384 * 128);
  const float* bhd = bhh + dir * 384;
  for (int g3 = 0; g3 < 3; ++g3) {
    const int R = g3 * 128 + gbase;
    for (int kf = 0; kf < 4; ++kf)
      af[g3][kf] = cvt8(&whd[(size_t)(R + ln) * 128 + kf * 32 + q * 8]);
  }
  for (int r = 0; r < 4; ++r) hbn[r] = bhd[256 + gbase + q * 4 + r];
  float h[4] = {0.f, 0.f, 0.f, 0.f};
  const int b = bbase + ln;
  __syncthreads();

  float4 Vr[4], Vz[4], Vn[4];
#define GLOAD_S(slot, st)                                                   \
  do {                                                                      \
    int tt_ = (st) > (S_ - 1) ? (S_ - 1) : (st);                            \
    int sg_ = dir ? (S_ - 1 - tt_) : tt_;                                   \
    const float* xp_ = xgi + ((size_t)dir * 2048 + sg_ * 64 + b) * 384 + g0;\
    Vr[slot] = *(const float4*)&xp_[0];                                     \
    Vz[slot] = *(const float4*)&xp_[128];                                   \
    Vn[slot] = *(const float4*)&xp_[256];                                   \
  } while (0)

  GLOAD_S(0, 0);
  GLOAD_S(1, 1);
  GLOAD_S(2, 2);

  int p = 0;
  for (int it = 0; it < S_ / 4; ++it) {
#pragma unroll
    for (int j = 0; j < 4; ++j) {
      const int step = it * 4 + j;
      const int sI = dir ? (S_ - 1 - step) : step;
      GLOAD_S((j + 3) & 3, step + 3);

      s8v bfr[4];
      for (int kf = 0; kf < 4; ++kf)
        bfr[kf] = *(const s8v*)&hb[p][ln * 136 + kf * 32 + q * 8];
      f32x4 c0 = {0.f, 0.f, 0.f, 0.f}, c1 = c0, c2 = c0;
      for (int kf = 0; kf < 4; ++kf) {
        c0 = mfma16(af[0][kf], bfr[kf], c0);
        c1 = mfma16(af[1][kf], bfr[kf], c1);
        c2 = mfma16(af[2][kf], bfr[kf], c2);
      }
      const float irv[4] = {Vr[j].x, Vr[j].y, Vr[j].z, Vr[j].w};
      const float izv[4] = {Vz[j].x, Vz[j].y, Vz[j].z, Vz[j].w};
      const float inv[4] = {Vn[j].x, Vn[j].y, Vn[j].z, Vn[j].w};
      unsigned short hnb[4];
      for (int r = 0; r < 4; ++r) {
        float rr = fsigm(irv[r] + c0[r]);
        float zz = fsigm(izv[r] + c1[r]);
        float nn = ftanh(inv[r] + rr * (c2[r] + hbn[r]));
        float hv = zz * (h[r] - nn) + nn;
        h[r] = hv;
        hnb[r] = f2b(hv);
      }
      ushort4 hv4; hv4.x = hnb[0]; hv4.y = hnb[1]; hv4.z = hnb[2]; hv4.w = hnb[3];
      *(ushort4*)&hb[p ^ 1][ln * 136 + g0] = hv4;
      float4 of4; of4.x = h[0]; of4.y = h[1]; of4.z = h[2]; of4.w = h[3];
      *(float4*)&io2[((size_t)(sI * 64 + b)) * 256 + dir * 128 + g0] = of4;
      lds_barrier();
      p ^= 1;
    }
  }
#undef GLOAD_S
}

// ============================================================================
// K6: a2[s*64+b] = proj_inter . tanh(io2 @ W_W_inter + b_inter)  (no softmax)
// ============================================================================
__global__ __launch_bounds__(256) void k_attn_i(
    const float* __restrict__ io2,
    const float* __restrict__ wwI,   // [256][256] fp32 h-major
    const float* __restrict__ bI,
    const float* __restrict__ projI,
    float* __restrict__ a2)          // [2048]
{
  const int bid = blockIdx.x, tid = threadIdx.x;
  const int r0 = bid * 8;
  __shared__ float iol[8 * 256];
  __shared__ float red[4 * 8];
  for (int i = 0; i < 8; ++i) iol[i * 256 + tid] = io2[(size_t)(r0 + i) * 256 + tid];
  __syncthreads();
  float acc[8];
  for (int i = 0; i < 8; ++i) acc[i] = 0.f;
  for (int hh = 0; hh < 256; ++hh) {
    const float wv = wwI[hh * 256 + tid];
    for (int i = 0; i < 8; ++i) acc[i] += wv * iol[i * 256 + hh];
  }
  const float bb = bI[tid], pp = projI[tid];
  float p[8];
  for (int i = 0; i < 8; ++i) p[i] = pp * ftanh(acc[i] + bb);
  for (int d = 1; d < 64; d <<= 1)
    for (int i = 0; i < 8; ++i) p[i] += __shfl_xor(p[i], d);
  const int w = tid >> 6, l = tid & 63;
  if (l == 0)
    for (int i = 0; i < 8; ++i) red[w * 8 + i] = p[i];
  __syncthreads();
  if (tid < 8) a2[r0 + tid] = red[tid] + red[8 + tid] + red[16 + tid] + red[24 + tid];
}

// ============================================================================
// K7: doc_vec = sum_s a2 * io2 ; out = doc @ W_final^T + b_final  (fp32 out)
// ============================================================================
__global__ __launch_bounds__(256) void k_final(
    const float* __restrict__ a2,
    const float* __restrict__ io2,
    const float* __restrict__ wf,    // [5][256] fp32
    const float* __restrict__ bfi,   // [5] fp32
    float* __restrict__ out)         // [64][5] fp32
{
  const int b = blockIdx.x, tid = threadIdx.x;
  __shared__ float av[S_];
  __shared__ float dv[256];
  __shared__ float red[4];
  if (tid < S_) av[tid] = a2[tid * 64 + b];
  __syncthreads();
  float acc = 0.f;
  for (int s = 0; s < S_; ++s) acc += av[s] * io2[((size_t)(s * 64 + b)) * 256 + tid];
  dv[tid] = acc;
  __syncthreads();
  for (int c = 0; c < C_; ++c) {
    float pv = wf[c * 256 + tid] * dv[tid];
    for (int d = 1; d < 64; d <<= 1) pv += __shfl_xor(pv, d);
    const int w = tid >> 6, l = tid & 63;
    if (l == 0) red[w] = pv;
    __syncthreads();
    if (tid == 0)
      out[b * C_ + c] = red[0] + red[1] + red[2] + red[3] + bfi[c];
    __syncthreads();
  }
}

// ============================================================================
extern "C" void kernel_launch(void* const* d_in, const int* in_sizes, int n_in,
                              void* d_out, int out_size, void* d_ws, size_t ws_size,
                              hipStream_t stream) {
  (void)in_sizes; (void)n_in; (void)out_size; (void)ws_size;
  const int*   tokens = (const int*)d_in[0];
  const float* emb    = (const float*)d_in[1];
  const float* wih_a  = (const float*)d_in[2];
  const float* whh_a  = (const float*)d_in[3];
  const float* bih_a  = (const float*)d_in[4];
  const float* bhh_a  = (const float*)d_in[5];
  const float* ww_a   = (const float*)d_in[6];
  const float* b_a    = (const float*)d_in[7];
  const float* proj_a = (const float*)d_in[8];
  const float* wih_i  = (const float*)d_in[9];
  const float* whh_i  = (const float*)d_in[10];
  const float* bih_i  = (const float*)d_in[11];
  const float* bhh_i  = (const float*)d_in[12];
  const float* ww_i   = (const float*)d_in[13];
  const float* b_i    = (const float*)d_in[14];
  const float* proj_i = (const float*)d_in[15];
  const float* w_fin  = (const float*)d_in[16];
  const float* b_fin  = (const float*)d_in[17];

  char* ws = (char*)d_ws;
  unsigned short* gtab = (unsigned short*)(ws + 0);          // 49,152,000 B
  unsigned short* wta  = (unsigned short*)(ws + 49152000);   //    131,072 B
  unsigned short* iout = (unsigned short*)(ws + 49283072);   // 67,108,864 B
  unsigned short* wib  = (unsigned short*)(ws + 116391936);  //    393,216 B
  float* xgi = (float*)(ws + 119537664);                     //  6,291,456 B
  float* io2 = (float*)(ws + 125829120);                     //  2,097,152 B
  float* a2  = (float*)(ws + 127926272);                     //      8,192 B

  k_gtab<<<508, 256, 0, stream>>>(emb, wih_a, bih_a, bhh_a, ww_a, wih_i,
                                  gtab, wta, wib);
  k_intra<<<256, 512, 0, stream>>>(tokens, gtab, whh_a, bhh_a, iout);
  k_attn<<<256, 512, 0, stream>>>(iout, wta, b_a, proj_a, wib, bih_i, bhh_i, xgi);
  k_inter<<<8, 512, 0, stream>>>(xgi, whh_i, bhh_i, io2);
  k_attn_i<<<256, 256, 0, stream>>>(io2, ww_i, b_i, proj_i, a2);
  k_final<<<64, 256, 0, stream>>>(a2, io2, w_fin, b_fin, (float*)d_out);
}